// Round 6
// baseline (3653.793 us; speedup 1.0000x reference)
//
#include <hip/hip_runtime.h>
#include <cstddef>

#define TE 48          // edges per block
#define NTHREADS 512
#define WR 8           // W-chunk rows
#define NCHUNK 112     // 48 (L1: K=384) + 32 (L2: K=256) + 32 (L3: K=256)

// LDS layout (float offsets)
#define SH_OFF    0                    // 12288 floats: H/R tile [48][256]; first 6144 alias A tile [48][128]
#define SW_OFF    12288                // 4096 floats: W double-buffer [2][8][256]
#define SW2_OFF   (SW_OFF + 4096)      // 256 floats: [pw2 | vw2]
#define SLOSS_OFF (SW2_OFF + 256)      // 64 floats (48 used)
#define SROW_OFF  (SLOSS_OFF + 64)     // 64 ints (48 used)
#define SCOL_OFF  (SROW_OFF + 64)      // 64 ints (48 used)
#define SMEM_FLOATS (SCOL_OFF + 64)    // 16832 floats = 67328 B -> 2 blocks/CU

// Occupancy evidence (this toolchain, dynamic LDS):
//   VGPR  64 (r2)        -> 45% occ (2 blocks/CU)
//   VGPR 84/88/112       -> 23% occ (1 block/CU)
// Spill at the 64-cap was prologue-only (~16 dwords/thread/kernel) and harmless.
// So: force the 64 budget via launch_bounds(512,4) AND make the natural need
// ~58 regs (acc 6x4=24 + w16 + a4 + wv4 + addr) so the hot loop is clean.
__global__ __launch_bounds__(NTHREADS, 4)
void fused_edge_mlp(
    const float* __restrict__ x,
    const int*   __restrict__ edge_index,
    const float* __restrict__ gf,
    const int*   __restrict__ labels,
    const float* __restrict__ se_w1, const float* __restrict__ se_b1,
    const float* __restrict__ se_w2, const float* __restrict__ se_b2,
    const float* __restrict__ pw1,  const float* __restrict__ pb1,
    const float* __restrict__ pw2,  const float* __restrict__ pb2,
    const float* __restrict__ vw1,  const float* __restrict__ vb1,
    const float* __restrict__ vw2,  const float* __restrict__ vb2,
    float* __restrict__ out,        // out[0]=loss (finalize kernel), out[1..E]=actions
    float* __restrict__ ws_partial,
    int n_edges)
{
  extern __shared__ float smem[];
  float* sH    = smem + SH_OFF;
  float* sA    = smem + SH_OFF;     // alias: A tile only live during layer-1 chunks
  float* sW    = smem + SW_OFF;     // [2][8][256]
  float* sW2   = smem + SW2_OFF;
  float* sLoss = smem + SLOSS_OFF;
  int*   sRow  = (int*)(smem + SROW_OFF);
  int*   sCol  = (int*)(smem + SCOL_OFF);

  const int t  = threadIdx.x;
  const int e0 = blockIdx.x * TE;

  // register-tile mapping: 6 edges x 4 cols per thread over the [48 x 256] tile
  const int tc  = t & 31;           // 32 col groups of 4 -> 128 cols
  const int teh = t >> 5;           // 0..15
  const int te  = teh & 7;          // edge group: edges te*6 .. te*6+5
  const int ch  = teh >> 3;         // column half
  const int colBase = ch * 128 + tc * 4;

  // per-thread W-chunk slot: thread t stages float4 #t of an [8][256] chunk
  const int wr  = t >> 6;           // row 0..7 within chunk
  const int wc4 = t & 63;           // float4 col 0..63

  // ---- initial small loads ----
  if (t < TE) {
    int eg = e0 + t;
    sRow[t] = (eg < n_edges) ? edge_index[eg] : 0;
  } else if (t < 2 * TE) {
    int eg = e0 + (t - TE);
    sCol[t - TE] = (eg < n_edges) ? edge_index[(size_t)n_edges + eg] : 0;
  } else if (t >= 128 && t < 384) {
    int c = t - 128;
    sW2[c] = (c < 128) ? pw2[c] : vw2[c - 128];
  }

  float acc[6][4];
  auto zero_acc = [&]() {
    #pragma unroll
    for (int i = 0; i < 6; ++i)
      #pragma unroll
      for (int j = 0; j < 4; ++j) acc[i][j] = 0.f;
  };

  // global chunk index -> this thread's float4 of that [8][256] W chunk
  // chunks: [0,48) se_w1; [48,80) se_w2; [80,112) [pw1|vw1]
  auto loadW = [&](int c) -> float4 {
    if (c < 48)
      return *(const float4*)&se_w1[((size_t)(c * WR + wr)) * 256 + wc4 * 4];
    if (c < 80)
      return *(const float4*)&se_w2[((size_t)((c - 48) * WR + wr)) * 256 + wc4 * 4];
    int row = (c - 80) * WR + wr;
    if (wc4 < 32) return *(const float4*)&pw1[(size_t)row * 128 + wc4 * 4];
    else          return *(const float4*)&vw1[(size_t)row * 128 + (wc4 - 32) * 4];
  };

  // acc += A[48 x 8] (row stride LDA) @ Wb[8][256], this thread's 6x4 sub-tile.
  // W hoisted per k4 (16 regs); one A row live at a time (broadcast read).
  auto gemm6 = [&](const float* Ak, const int LDA, const float* Wb) {
    #pragma unroll
    for (int k4 = 0; k4 < 2; ++k4) {
      float4 w0 = *(const float4*)&Wb[(k4 * 4 + 0) * 256 + colBase];
      float4 w1 = *(const float4*)&Wb[(k4 * 4 + 1) * 256 + colBase];
      float4 w2 = *(const float4*)&Wb[(k4 * 4 + 2) * 256 + colBase];
      float4 w3 = *(const float4*)&Wb[(k4 * 4 + 3) * 256 + colBase];
      #pragma unroll
      for (int i = 0; i < 6; ++i) {
        float4 a = *(const float4*)&Ak[(te * 6 + i) * LDA + k4 * 4];
        acc[i][0] = fmaf(a.x, w0.x, acc[i][0]);
        acc[i][1] = fmaf(a.x, w0.y, acc[i][1]);
        acc[i][2] = fmaf(a.x, w0.z, acc[i][2]);
        acc[i][3] = fmaf(a.x, w0.w, acc[i][3]);
        acc[i][0] = fmaf(a.y, w1.x, acc[i][0]);
        acc[i][1] = fmaf(a.y, w1.y, acc[i][1]);
        acc[i][2] = fmaf(a.y, w1.z, acc[i][2]);
        acc[i][3] = fmaf(a.y, w1.w, acc[i][3]);
        acc[i][0] = fmaf(a.z, w2.x, acc[i][0]);
        acc[i][1] = fmaf(a.z, w2.y, acc[i][1]);
        acc[i][2] = fmaf(a.z, w2.z, acc[i][2]);
        acc[i][3] = fmaf(a.z, w2.w, acc[i][3]);
        acc[i][0] = fmaf(a.w, w3.x, acc[i][0]);
        acc[i][1] = fmaf(a.w, w3.y, acc[i][1]);
        acc[i][2] = fmaf(a.w, w3.z, acc[i][2]);
        acc[i][3] = fmaf(a.w, w3.w, acc[i][3]);
      }
    }
  };

  // A-tile gather for layer-1 segment: [48][128], 1536 float4 / 512 thr = 3 each
  auto stageA = [&](int seg) {
    const float* src = (seg == 2) ? gf : x;
    const int*   idx = (seg == 0) ? sRow : sCol;
    float4 tmp[3];
    #pragma unroll
    for (int j = 0; j < 3; ++j) {
      int i4  = t + j * NTHREADS;   // 0..1535
      int r   = i4 >> 5;            // 0..47
      int cf4 = i4 & 31;            // 0..31
      tmp[j] = *(const float4*)&src[(size_t)idx[r] * 128 + cf4 * 4];
    }
    #pragma unroll
    for (int j = 0; j < 3; ++j) {
      int i4 = t + j * NTHREADS;
      *(float4*)&sA[i4 * 4] = tmp[j];
    }
  };

  auto epilogue = [&](const float* bias, bool relu) {
    float4 b = *(const float4*)&bias[ch ? (colBase - 128) * 0 + colBase : colBase];
    (void)b;  // (specialized below per layer; kept simple at call sites)
  };
  (void)epilogue;

  // ---- prologue: prime W pipeline + first A segment ----
  float4 w0v = loadW(0);
  float4 wv  = loadW(1);
  __syncthreads();                     // sRow/sCol visible
  stageA(0);
  *(float4*)&sW[t * 4] = w0v;          // chunk 0 -> buf 0
  __syncthreads();                     // sA seg0 + buf0 ready

  zero_acc();

  // ---- unified chunk loop: 1 barrier per chunk, W double-buffered ----
  for (int c = 0; c < NCHUNK; ++c) {
    if (c == 16 || c == 32) {          // new A segment (prev reads drained by c-1's barrier)
      stageA(c >> 4);
      __syncthreads();
    }
    if (c + 1 < NCHUNK)
      *(float4*)&sW[((c + 1) & 1) * 2048 + t * 4] = wv;  // write next chunk (buf last read at c-1)
    if (c + 2 < NCHUNK)
      wv = loadW(c + 2);                                  // 2-ahead prefetch (latency hidden)

    const float* Wb = sW + (c & 1) * 2048;
    if (c < 48)      gemm6(sA + (c & 15) * WR, 128, Wb);
    else if (c < 80) gemm6(sH + (c - 48) * WR, 256, Wb);
    else             gemm6(sH + (c - 80) * WR, 256, Wb);

    __syncthreads();   // gemm reads of buf[c&1] + writes of buf[(c+1)&1] drained

    if (c == 47) {     // L1 epilogue: relu(acc+b1) -> sH (overwrites sA alias)
      float4 b = *(const float4*)&se_b1[colBase];
      #pragma unroll
      for (int i = 0; i < 6; ++i) {
        float4 hv;
        hv.x = fmaxf(acc[i][0] + b.x, 0.f);
        hv.y = fmaxf(acc[i][1] + b.y, 0.f);
        hv.z = fmaxf(acc[i][2] + b.z, 0.f);
        hv.w = fmaxf(acc[i][3] + b.w, 0.f);
        *(float4*)&sH[(te * 6 + i) * 256 + colBase] = hv;
      }
      zero_acc();
      __syncthreads();
    } else if (c == 79) {  // L2 epilogue: acc+b2 -> sH (no relu)
      float4 b = *(const float4*)&se_b2[colBase];
      #pragma unroll
      for (int i = 0; i < 6; ++i) {
        float4 hv;
        hv.x = acc[i][0] + b.x;
        hv.y = acc[i][1] + b.y;
        hv.z = acc[i][2] + b.z;
        hv.w = acc[i][3] + b.w;
        *(float4*)&sH[(te * 6 + i) * 256 + colBase] = hv;
      }
      zero_acc();
      __syncthreads();
    }
  }

  // L3 epilogue: relu(acc + [pb1|vb1]) -> sH
  {
    float4 b = (ch == 0) ? *(const float4*)&pb1[tc * 4] : *(const float4*)&vb1[tc * 4];
    #pragma unroll
    for (int i = 0; i < 6; ++i) {
      float4 hv;
      hv.x = fmaxf(acc[i][0] + b.x, 0.f);
      hv.y = fmaxf(acc[i][1] + b.y, 0.f);
      hv.z = fmaxf(acc[i][2] + b.z, 0.f);
      hv.w = fmaxf(acc[i][3] + b.w, 0.f);
      *(float4*)&sH[(te * 6 + i) * 256 + colBase] = hv;
    }
  }
  __syncthreads();

  // ================= Layer 4: heads (two 128-dots per edge) =================
  if (t < 4 * 2 * TE) {        // 384 threads
    int lk   = t & 3;          // k quarter
    int d    = t >> 2;         // 0..95
    int head = (d >= TE);      // 0: policy, 1: value
    int edge = d - head * TE;  // 0..47
    int base = head * 128 + lk * 32;
    float p = 0.f;
    #pragma unroll
    for (int kk = 0; kk < 32; kk += 4) {
      float4 r4 = *(const float4*)&sH[edge * 256 + base + kk];
      float4 w4 = *(const float4*)&sW2[base + kk];
      p = fmaf(r4.x, w4.x, p);
      p = fmaf(r4.y, w4.y, p);
      p = fmaf(r4.z, w4.z, p);
      p = fmaf(r4.w, w4.w, p);
    }
    p += __shfl_xor(p, 1);
    p += __shfl_xor(p, 2);
    if (lk == 0) {
      int eg = e0 + edge;
      bool valid = eg < n_edges;
      if (head == 0) {
        float logit = p + pb2[0];
        if (valid) out[1 + eg] = (logit > 0.f) ? 1.f : 0.f;  // sigmoid(l)>0.5 <=> l>0
      } else {
        float term = 0.f;
        if (valid) {
          float z = p + vb2[0];
          float yv = (float)labels[sRow[edge]];
          term = fmaxf(z, 0.f) - z * yv + log1pf(expf(-fabsf(z)));
        }
        sLoss[edge] = term;
      }
    }
  }
  __syncthreads();
  if (t == 0) {
    float s = 0.f;
    #pragma unroll 4
    for (int i = 0; i < TE; ++i) s += sLoss[i];  // fixed order -> deterministic
    ws_partial[blockIdx.x] = s;
  }
}

__global__ void finalize_loss(const float* __restrict__ ws, float* __restrict__ out,
                              int n, double invE)
{
  __shared__ double sd[256];
  double a = 0.0;
  for (int i = threadIdx.x; i < n; i += 256) a += (double)ws[i];  // fixed order
  sd[threadIdx.x] = a;
  __syncthreads();
  for (int off = 128; off > 0; off >>= 1) {
    if ((int)threadIdx.x < off) sd[threadIdx.x] += sd[threadIdx.x + off];
    __syncthreads();
  }
  if (threadIdx.x == 0) out[0] = (float)(sd[0] * invE);
}

extern "C" void kernel_launch(void* const* d_in, const int* in_sizes, int n_in,
                              void* d_out, int out_size, void* d_ws, size_t ws_size,
                              hipStream_t stream) {
  const float* x      = (const float*)d_in[0];
  const int*   ei     = (const int*)  d_in[1];
  const float* gf     = (const float*)d_in[2];
  const int*   labels = (const int*)  d_in[3];
  const float* se_w1  = (const float*)d_in[4];
  const float* se_b1  = (const float*)d_in[5];
  const float* se_w2  = (const float*)d_in[6];
  const float* se_b2  = (const float*)d_in[7];
  const float* pw1    = (const float*)d_in[8];
  const float* pb1    = (const float*)d_in[9];
  const float* pw2    = (const float*)d_in[10];
  const float* pb2    = (const float*)d_in[11];
  const float* vw1    = (const float*)d_in[12];
  const float* vb1    = (const float*)d_in[13];
  const float* vw2    = (const float*)d_in[14];
  const float* vb2    = (const float*)d_in[15];

  int n_edges = in_sizes[1] / 2;
  int nblocks = (n_edges + TE - 1) / TE;
  float* out = (float*)d_out;
  float* ws  = (float*)d_ws;

  size_t shmem = SMEM_FLOATS * sizeof(float);  // 67328 B -> 2 blocks/CU
  (void)hipFuncSetAttribute((const void*)fused_edge_mlp,
                            hipFuncAttributeMaxDynamicSharedMemorySize, (int)shmem);

  fused_edge_mlp<<<dim3(nblocks), dim3(NTHREADS), shmem, stream>>>(
      x, ei, gf, labels,
      se_w1, se_b1, se_w2, se_b2,
      pw1, pb1, pw2, pb2,
      vw1, vb1, vw2, vb2,
      out, ws, n_edges);

  finalize_loss<<<dim3(1), dim3(256), 0, stream>>>(ws, out, nblocks, 1.0 / (double)n_edges);
}

// Round 7
// 2727.703 us; speedup vs baseline: 1.3395x; 1.3395x over previous
//
#include <hip/hip_runtime.h>
#include <cstddef>

#define TE 56          // edges per block -> acc 7x4 per thread
#define NTHREADS 512

// LDS layout (float offsets) — total 75520 B, the footprint PROVEN to give
// 2 blocks/CU (r2: 45% occupancy).
#define SH_OFF    0                    // [56][256] = 14336 floats; first 7168 alias A tile [56][128]
#define SW_OFF    14336                // W double-buffer [2][8][256] = 4096 floats
#define SW2_OFF   (SW_OFF + 4096)      // 256 floats: [pw2 | vw2]
#define SLOSS_OFF (SW2_OFF + 256)      // 64 floats (56 used)
#define SROW_OFF  (SLOSS_OFF + 64)     // 64 ints
#define SCOL_OFF  (SROW_OFF + 64)      // 64 ints
#define SMEM_FLOATS (SCOL_OFF + 64)    // 18880 floats = 75520 B

// Occupancy model fitting r1-r6: waves/SIMD = floor(256/VGPR).
//   64 VGPR -> 4 waves/SIMD (2 blocks/CU, 45%);  84-112 VGPR -> 2 (1 block, 23%).
// So VGPR<=64 is mandatory. Prior rounds spilled under the cap because W/A
// staging went through registers (wv/tmp/a[][] = +16..48 live). This version
// stages via global_load_lds (HBM->LDS direct, 0 VGPRs, no ds_write):
// natural need = acc28 + w16 + a4 + addr ~ 56 < 64 -> no spill.
__device__ __forceinline__ void gld16(const float* g, float* l) {
  __builtin_amdgcn_global_load_lds(
      (const __attribute__((address_space(1))) void*)g,
      (__attribute__((address_space(3))) void*)l, 16, 0, 0);
}

__global__ __launch_bounds__(NTHREADS, 4)
void fused_edge_mlp(
    const float* __restrict__ x,
    const int*   __restrict__ edge_index,
    const float* __restrict__ gf,
    const int*   __restrict__ labels,
    const float* __restrict__ se_w1, const float* __restrict__ se_b1,
    const float* __restrict__ se_w2, const float* __restrict__ se_b2,
    const float* __restrict__ pw1,  const float* __restrict__ pb1,
    const float* __restrict__ pw2,  const float* __restrict__ pb2,
    const float* __restrict__ vw1,  const float* __restrict__ vb1,
    const float* __restrict__ vw2,  const float* __restrict__ vb2,
    float* __restrict__ out,        // out[0]=loss (finalize), out[1..E]=actions
    float* __restrict__ ws_partial,
    int n_edges)
{
  extern __shared__ float smem[];
  float* sH    = smem + SH_OFF;
  float* sA    = smem + SH_OFF;     // alias: A tile live only during L1 chunks
  float* sW    = smem + SW_OFF;     // [2][8][256]
  float* sW2   = smem + SW2_OFF;
  float* sLoss = smem + SLOSS_OFF;
  int*   sRow  = (int*)(smem + SROW_OFF);
  int*   sCol  = (int*)(smem + SCOL_OFF);

  const int t  = threadIdx.x;
  const int e0 = blockIdx.x * TE;

  // register tile: 7 edges x 4 cols per thread over [56 x 256]
  const int tc  = t & 31;
  const int teh = t >> 5;
  const int te  = teh & 7;          // edge group: rows te*7 .. te*7+6
  const int ch  = teh >> 3;
  const int colBase = ch * 128 + tc * 4;

  // W-chunk staging slot: thread t stages float4 #t of an [8][256] chunk
  const int wr  = t >> 6;           // = wave id: dest is wave-uniform + lane*16
  const int wc4 = t & 63;

  // ---- prologue small stages (regular stores) ----
  if (t < TE) {
    int eg = e0 + t;
    sRow[t] = (eg < n_edges) ? edge_index[eg] : 0;
  } else if (t < 2 * TE) {
    int eg = e0 + (t - TE);
    sCol[t - TE] = (eg < n_edges) ? edge_index[(size_t)n_edges + eg] : 0;
  } else if (t >= 128 && t < 384) {
    int c = t - 128;
    sW2[c] = (c < 128) ? pw2[c] : vw2[c - 128];
  }

  float acc[7][4];
  auto zero_acc = [&]() {
    #pragma unroll
    for (int i = 0; i < 7; ++i)
      #pragma unroll
      for (int j = 0; j < 4; ++j) acc[i][j] = 0.f;
  };

  // async W-chunk stagers: one global_load_lds dwordx4 per thread
  auto issueW1 = [&](int c, int b) {
    gld16(&se_w1[((size_t)(c * 8 + wr)) * 256 + wc4 * 4], &sW[b * 2048 + t * 4]);
  };
  auto issueW2 = [&](int c, int b) {
    gld16(&se_w2[((size_t)(c * 8 + wr)) * 256 + wc4 * 4], &sW[b * 2048 + t * 4]);
  };
  auto issueW3 = [&](int c, int b) {
    int row = c * 8 + wr;
    const float* src = (wc4 < 32) ? &pw1[(size_t)row * 128 + wc4 * 4]
                                  : &vw1[(size_t)row * 128 + (wc4 - 32) * 4];
    gld16(src, &sW[b * 2048 + t * 4]);
  };

  // async A-tile gather: [56][128] = 1792 float4; per-lane gathered source is
  // legal for global_load_lds (LDS dest stays linear: uniform + lane*16)
  auto stageA_issue = [&](int seg) {
    const float* src = (seg == 2) ? gf : x;
    const int*   idx = (seg == 0) ? sRow : sCol;
    #pragma unroll
    for (int j = 0; j < 3; ++j) {
      int i4 = t + j * NTHREADS;
      int r = i4 >> 5, c4 = i4 & 31;
      gld16(&src[(size_t)idx[r] * 128 + c4 * 4], &sA[i4 * 4]);
    }
    if (t < 256) {
      int i4 = t + 3 * NTHREADS;
      int r = i4 >> 5, c4 = i4 & 31;
      gld16(&src[(size_t)idx[r] * 128 + c4 * 4], &sA[i4 * 4]);
    }
  };

  // acc += A[56 x 8](stride LDA) @ Wb[8][256], this thread's 7x4 sub-tile
  auto gemmC = [&](const float* Ak, const int LDA, const float* Wb) {
    #pragma unroll
    for (int k4 = 0; k4 < 2; ++k4) {
      float4 w0 = *(const float4*)&Wb[(k4 * 4 + 0) * 256 + colBase];
      float4 w1 = *(const float4*)&Wb[(k4 * 4 + 1) * 256 + colBase];
      float4 w2 = *(const float4*)&Wb[(k4 * 4 + 2) * 256 + colBase];
      float4 w3 = *(const float4*)&Wb[(k4 * 4 + 3) * 256 + colBase];
      #pragma unroll
      for (int i = 0; i < 7; ++i) {
        float4 a = *(const float4*)&Ak[(te * 7 + i) * LDA + k4 * 4];
        acc[i][0] = fmaf(a.x, w0.x, acc[i][0]);
        acc[i][1] = fmaf(a.x, w0.y, acc[i][1]);
        acc[i][2] = fmaf(a.x, w0.z, acc[i][2]);
        acc[i][3] = fmaf(a.x, w0.w, acc[i][3]);
        acc[i][0] = fmaf(a.y, w1.x, acc[i][0]);
        acc[i][1] = fmaf(a.y, w1.y, acc[i][1]);
        acc[i][2] = fmaf(a.y, w1.z, acc[i][2]);
        acc[i][3] = fmaf(a.y, w1.w, acc[i][3]);
        acc[i][0] = fmaf(a.z, w2.x, acc[i][0]);
        acc[i][1] = fmaf(a.z, w2.y, acc[i][1]);
        acc[i][2] = fmaf(a.z, w2.z, acc[i][2]);
        acc[i][3] = fmaf(a.z, w2.w, acc[i][3]);
        acc[i][0] = fmaf(a.w, w3.x, acc[i][0]);
        acc[i][1] = fmaf(a.w, w3.y, acc[i][1]);
        acc[i][2] = fmaf(a.w, w3.z, acc[i][2]);
        acc[i][3] = fmaf(a.w, w3.w, acc[i][3]);
      }
    }
  };

  // ---- prologue: W0 + A seg0 in flight ----
  issueW1(0, 0);
  __syncthreads();              // sRow/sCol visible (also drains W0 early)
  stageA_issue(0);
  __syncthreads();              // A seg0 + W0 ready

  zero_acc();

  // ================= Layer 1: 48 chunks (K=384), W dbuf, 1 barrier/chunk ==========
  #pragma unroll 2
  for (int c = 0; c < 48; ++c) {
    bool segb = (c == 16) | (c == 32);
    if (segb) stageA_issue(c >> 4);          // next A segment (prev fully read)
    if (c < 47) issueW1(c + 1, (c + 1) & 1);
    else        issueW2(0, 0);               // cross-layer prefetch (48&1==0)
    if (segb) __syncthreads();               // drain new A before using it
    gemmC(sA + (c & 15) * 8, 128, sW + (c & 1) * 2048);
    __syncthreads();                         // W(c+1)/A drained; buf[c&1] free
  }

  { // L1 epilogue: relu(acc+b1) -> sH (overwrites sA alias; reads done at c=47 sync)
    float4 b = *(const float4*)&se_b1[colBase];
    #pragma unroll
    for (int i = 0; i < 7; ++i) {
      float4 hv;
      hv.x = fmaxf(acc[i][0] + b.x, 0.f);
      hv.y = fmaxf(acc[i][1] + b.y, 0.f);
      hv.z = fmaxf(acc[i][2] + b.z, 0.f);
      hv.w = fmaxf(acc[i][3] + b.w, 0.f);
      *(float4*)&sH[(te * 7 + i) * 256 + colBase] = hv;
    }
    zero_acc();
  }
  __syncthreads();   // H1 visible; W2 chunk0 (issued at c=47) drained into buf0

  // ================= Layer 2: 32 chunks (K=256) =================
  #pragma unroll 2
  for (int c = 0; c < 32; ++c) {
    if (c < 31) issueW2(c + 1, (c + 1) & 1);
    else        issueW3(0, 0);               // (global chunk 80)&1==0
    gemmC(sH + c * 8, 256, sW + (c & 1) * 2048);
    __syncthreads();
  }

  { // L2 epilogue: acc+b2 -> sH (no relu)
    float4 b = *(const float4*)&se_b2[colBase];
    #pragma unroll
    for (int i = 0; i < 7; ++i) {
      float4 hv;
      hv.x = acc[i][0] + b.x;
      hv.y = acc[i][1] + b.y;
      hv.z = acc[i][2] + b.z;
      hv.w = acc[i][3] + b.w;
      *(float4*)&sH[(te * 7 + i) * 256 + colBase] = hv;
    }
    zero_acc();
  }
  __syncthreads();

  // ============ Layer 3: 32 chunks (K=256), cols = [pw1|vw1] ============
  #pragma unroll 2
  for (int c = 0; c < 32; ++c) {
    if (c < 31) issueW3(c + 1, (c + 1) & 1);
    gemmC(sH + c * 8, 256, sW + (c & 1) * 2048);
    __syncthreads();
  }

  { // L3 epilogue: relu(acc + [pb1|vb1]) -> sH
    float4 b = (ch == 0) ? *(const float4*)&pb1[tc * 4] : *(const float4*)&vb1[tc * 4];
    #pragma unroll
    for (int i = 0; i < 7; ++i) {
      float4 hv;
      hv.x = fmaxf(acc[i][0] + b.x, 0.f);
      hv.y = fmaxf(acc[i][1] + b.y, 0.f);
      hv.z = fmaxf(acc[i][2] + b.z, 0.f);
      hv.w = fmaxf(acc[i][3] + b.w, 0.f);
      *(float4*)&sH[(te * 7 + i) * 256 + colBase] = hv;
    }
  }
  __syncthreads();

  // ================= Layer 4: heads (two 128-dots per edge) =================
  if (t < 4 * 2 * TE) {        // 448 threads
    int lk   = t & 3;          // k quarter
    int d    = t >> 2;         // 0..111
    int head = (d >= TE);      // 0: policy, 1: value
    int edge = d - head * TE;  // 0..55
    int base = head * 128 + lk * 32;
    float p = 0.f;
    #pragma unroll
    for (int kk = 0; kk < 32; kk += 4) {
      float4 r4 = *(const float4*)&sH[edge * 256 + base + kk];
      float4 w4 = *(const float4*)&sW2[base + kk];
      p = fmaf(r4.x, w4.x, p);
      p = fmaf(r4.y, w4.y, p);
      p = fmaf(r4.z, w4.z, p);
      p = fmaf(r4.w, w4.w, p);
    }
    p += __shfl_xor(p, 1);
    p += __shfl_xor(p, 2);
    if (lk == 0) {
      int eg = e0 + edge;
      bool valid = eg < n_edges;
      if (head == 0) {
        float logit = p + pb2[0];
        if (valid) out[1 + eg] = (logit > 0.f) ? 1.f : 0.f;  // sigmoid(l)>0.5 <=> l>0
      } else {
        float term = 0.f;
        if (valid) {
          float z = p + vb2[0];
          float yv = (float)labels[sRow[edge]];
          term = fmaxf(z, 0.f) - z * yv + log1pf(expf(-fabsf(z)));
        }
        sLoss[edge] = term;
      }
    }
  }
  __syncthreads();
  if (t == 0) {
    float s = 0.f;
    #pragma unroll 4
    for (int i = 0; i < TE; ++i) s += sLoss[i];  // fixed order -> deterministic
    ws_partial[blockIdx.x] = s;
  }
}

__global__ void finalize_loss(const float* __restrict__ ws, float* __restrict__ out,
                              int n, double invE)
{
  __shared__ double sd[256];
  double a = 0.0;
  for (int i = threadIdx.x; i < n; i += 256) a += (double)ws[i];  // fixed order
  sd[threadIdx.x] = a;
  __syncthreads();
  for (int off = 128; off > 0; off >>= 1) {
    if ((int)threadIdx.x < off) sd[threadIdx.x] += sd[threadIdx.x + off];
    __syncthreads();
  }
  if (threadIdx.x == 0) out[0] = (float)(sd[0] * invE);
}

extern "C" void kernel_launch(void* const* d_in, const int* in_sizes, int n_in,
                              void* d_out, int out_size, void* d_ws, size_t ws_size,
                              hipStream_t stream) {
  const float* x      = (const float*)d_in[0];
  const int*   ei     = (const int*)  d_in[1];
  const float* gf     = (const float*)d_in[2];
  const int*   labels = (const int*)  d_in[3];
  const float* se_w1  = (const float*)d_in[4];
  const float* se_b1  = (const float*)d_in[5];
  const float* se_w2  = (const float*)d_in[6];
  const float* se_b2  = (const float*)d_in[7];
  const float* pw1    = (const float*)d_in[8];
  const float* pb1    = (const float*)d_in[9];
  const float* pw2    = (const float*)d_in[10];
  const float* pb2    = (const float*)d_in[11];
  const float* vw1    = (const float*)d_in[12];
  const float* vb1    = (const float*)d_in[13];
  const float* vw2    = (const float*)d_in[14];
  const float* vb2    = (const float*)d_in[15];

  int n_edges = in_sizes[1] / 2;
  int nblocks = (n_edges + TE - 1) / TE;
  float* out = (float*)d_out;
  float* ws  = (float*)d_ws;

  size_t shmem = SMEM_FLOATS * sizeof(float);  // 75520 B -> 2 blocks/CU
  (void)hipFuncSetAttribute((const void*)fused_edge_mlp,
                            hipFuncAttributeMaxDynamicSharedMemorySize, (int)shmem);

  fused_edge_mlp<<<dim3(nblocks), dim3(NTHREADS), shmem, stream>>>(
      x, ei, gf, labels,
      se_w1, se_b1, se_w2, se_b2,
      pw1, pb1, pw2, pb2,
      vw1, vb1, vw2, vb2,
      out, ws, n_edges);

  finalize_loss<<<dim3(1), dim3(256), 0, stream>>>(ws, out, nblocks, 1.0 / (double)n_edges);
}

// Round 8
// 2677.674 us; speedup vs baseline: 1.3645x; 1.0187x over previous
//
#include <hip/hip_runtime.h>
#include <cstddef>

#define TE 56          // edges per block -> acc 7x4 per thread
#define NTHREADS 512

typedef float v2f __attribute__((ext_vector_type(2)));

// LDS layout (float offsets) — total 75520 B (proven 2 blocks/CU footprint)
#define SH_OFF    0                    // [56][256] = 14336 floats; first 7168 alias A tile [56][128]
#define SW_OFF    14336                // W double-buffer [2][8][256] = 4096 floats
#define SW2_OFF   (SW_OFF + 4096)      // 256 floats: [pw2 | vw2]
#define SLOSS_OFF (SW2_OFF + 256)      // 64 floats (56 used)
#define SROW_OFF  (SLOSS_OFF + 64)     // 64 ints
#define SCOL_OFF  (SROW_OFF + 64)      // 64 ints
#define SMEM_FLOATS (SCOL_OFF + 64)    // 18880 floats = 75520 B

// Occupancy model (r1-r7): waves/SIMD = floor(256/VGPR); VGPR<=64 mandatory for
// 2 blocks/CU. Staging via global_load_lds keeps reg need ~56. r7 landed VGPR 64,
// occ 46%, VALU-busy time ~= scalar-FMA issue floor (m07 ~100 TF). This round:
// v_pk_fma_f32 via __builtin_elementwise_fma on float2 — halves hot-loop VALU
// instruction count; scalarizes harmlessly if the target lacks pk fp32.
__device__ __forceinline__ void gld16(const float* g, float* l) {
  __builtin_amdgcn_global_load_lds(
      (const __attribute__((address_space(1))) void*)g,
      (__attribute__((address_space(3))) void*)l, 16, 0, 0);
}

__global__ __launch_bounds__(NTHREADS, 4)
void fused_edge_mlp(
    const float* __restrict__ x,
    const int*   __restrict__ edge_index,
    const float* __restrict__ gf,
    const int*   __restrict__ labels,
    const float* __restrict__ se_w1, const float* __restrict__ se_b1,
    const float* __restrict__ se_w2, const float* __restrict__ se_b2,
    const float* __restrict__ pw1,  const float* __restrict__ pb1,
    const float* __restrict__ pw2,  const float* __restrict__ pb2,
    const float* __restrict__ vw1,  const float* __restrict__ vb1,
    const float* __restrict__ vw2,  const float* __restrict__ vb2,
    float* __restrict__ out,        // out[0]=loss (finalize), out[1..E]=actions
    float* __restrict__ ws_partial,
    int n_edges)
{
  extern __shared__ float smem[];
  float* sH    = smem + SH_OFF;
  float* sA    = smem + SH_OFF;     // alias: A tile live only during L1 chunks
  float* sW    = smem + SW_OFF;     // [2][8][256]
  float* sW2   = smem + SW2_OFF;
  float* sLoss = smem + SLOSS_OFF;
  int*   sRow  = (int*)(smem + SROW_OFF);
  int*   sCol  = (int*)(smem + SCOL_OFF);

  const int t  = threadIdx.x;
  const int e0 = blockIdx.x * TE;

  // register tile: 7 edges x 4 cols per thread over [56 x 256]
  const int tc  = t & 31;
  const int teh = t >> 5;
  const int te  = teh & 7;          // edge group: rows te*7 .. te*7+6
  const int ch  = teh >> 3;
  const int colBase = ch * 128 + tc * 4;

  // W-chunk staging slot: thread t stages float4 #t of an [8][256] chunk
  const int wr  = t >> 6;           // = wave id: LDS dest is wave-uniform + lane*16
  const int wc4 = t & 63;

  // ---- prologue small stages ----
  if (t < TE) {
    int eg = e0 + t;
    sRow[t] = (eg < n_edges) ? edge_index[eg] : 0;
  } else if (t < 2 * TE) {
    int eg = e0 + (t - TE);
    sCol[t - TE] = (eg < n_edges) ? edge_index[(size_t)n_edges + eg] : 0;
  } else if (t >= 128 && t < 384) {
    int c = t - 128;
    sW2[c] = (c < 128) ? pw2[c] : vw2[c - 128];
  }

  v2f acc[7][2];   // [edge][col-pair]: cols colBase+{0,1} and colBase+{2,3}
  auto zero_acc = [&]() {
    #pragma unroll
    for (int i = 0; i < 7; ++i) {
      acc[i][0] = v2f{0.f, 0.f};
      acc[i][1] = v2f{0.f, 0.f};
    }
  };

  // async W-chunk stagers: one global_load_lds dwordx4 per thread
  auto issueW1 = [&](int c, int b) {
    gld16(&se_w1[((size_t)(c * 8 + wr)) * 256 + wc4 * 4], &sW[b * 2048 + t * 4]);
  };
  auto issueW2 = [&](int c, int b) {
    gld16(&se_w2[((size_t)(c * 8 + wr)) * 256 + wc4 * 4], &sW[b * 2048 + t * 4]);
  };
  auto issueW3 = [&](int c, int b) {
    int row = c * 8 + wr;
    const float* src = (wc4 < 32) ? &pw1[(size_t)row * 128 + wc4 * 4]
                                  : &vw1[(size_t)row * 128 + (wc4 - 32) * 4];
    gld16(src, &sW[b * 2048 + t * 4]);
  };

  // async A-tile gather: [56][128] = 1792 float4 (per-lane gathered source ok;
  // LDS dest linear: uniform + lane*16)
  auto stageA_issue = [&](int seg) {
    const float* src = (seg == 2) ? gf : x;
    const int*   idx = (seg == 0) ? sRow : sCol;
    #pragma unroll
    for (int j = 0; j < 3; ++j) {
      int i4 = t + j * NTHREADS;
      int r = i4 >> 5, c4 = i4 & 31;
      gld16(&src[(size_t)idx[r] * 128 + c4 * 4], &sA[i4 * 4]);
    }
    if (t < 256) {
      int i4 = t + 3 * NTHREADS;
      int r = i4 >> 5, c4 = i4 & 31;
      gld16(&src[(size_t)idx[r] * 128 + c4 * 4], &sA[i4 * 4]);
    }
  };

  // acc += A[56 x 8](stride LDA) @ Wb[8][256], this thread's 7x4 sub-tile.
  // Inner op: v2f fma (v_pk_fma_f32 when available; scalarizes identically).
  auto gemmC = [&](const float* Ak, const int LDA, const float* Wb) {
    #pragma unroll
    for (int k4 = 0; k4 < 2; ++k4) {
      v2f w[4][2];
      #pragma unroll
      for (int dk = 0; dk < 4; ++dk) {
        float4 wv = *(const float4*)&Wb[(k4 * 4 + dk) * 256 + colBase];
        w[dk][0] = v2f{wv.x, wv.y};
        w[dk][1] = v2f{wv.z, wv.w};
      }
      #pragma unroll
      for (int i = 0; i < 7; ++i) {
        float4 a = *(const float4*)&Ak[(te * 7 + i) * LDA + k4 * 4];
        v2f a0 = v2f{a.x, a.x};
        v2f a1 = v2f{a.y, a.y};
        v2f a2 = v2f{a.z, a.z};
        v2f a3 = v2f{a.w, a.w};
        acc[i][0] = __builtin_elementwise_fma(a0, w[0][0], acc[i][0]);
        acc[i][1] = __builtin_elementwise_fma(a0, w[0][1], acc[i][1]);
        acc[i][0] = __builtin_elementwise_fma(a1, w[1][0], acc[i][0]);
        acc[i][1] = __builtin_elementwise_fma(a1, w[1][1], acc[i][1]);
        acc[i][0] = __builtin_elementwise_fma(a2, w[2][0], acc[i][0]);
        acc[i][1] = __builtin_elementwise_fma(a2, w[2][1], acc[i][1]);
        acc[i][0] = __builtin_elementwise_fma(a3, w[3][0], acc[i][0]);
        acc[i][1] = __builtin_elementwise_fma(a3, w[3][1], acc[i][1]);
      }
    }
  };

  // ---- prologue: W0 + A seg0 in flight ----
  issueW1(0, 0);
  __syncthreads();              // sRow/sCol visible
  stageA_issue(0);
  __syncthreads();              // A seg0 + W0 ready

  zero_acc();

  // ================= Layer 1: 48 chunks (K=384), W dbuf, 1 barrier/chunk ==========
  #pragma unroll 2
  for (int c = 0; c < 48; ++c) {
    bool segb = (c == 16) | (c == 32);
    if (segb) stageA_issue(c >> 4);          // next A segment (prev fully read)
    if (c < 47) issueW1(c + 1, (c + 1) & 1);
    else        issueW2(0, 0);               // cross-layer prefetch (48&1==0)
    if (segb) __syncthreads();               // drain new A before using it
    gemmC(sA + (c & 15) * 8, 128, sW + (c & 1) * 2048);
    __syncthreads();                         // W(c+1)/A drained; buf[c&1] free
  }

  { // L1 epilogue: relu(acc+b1) -> sH (overwrites sA alias)
    float4 b = *(const float4*)&se_b1[colBase];
    #pragma unroll
    for (int i = 0; i < 7; ++i) {
      float4 hv;
      hv.x = fmaxf(acc[i][0].x + b.x, 0.f);
      hv.y = fmaxf(acc[i][0].y + b.y, 0.f);
      hv.z = fmaxf(acc[i][1].x + b.z, 0.f);
      hv.w = fmaxf(acc[i][1].y + b.w, 0.f);
      *(float4*)&sH[(te * 7 + i) * 256 + colBase] = hv;
    }
    zero_acc();
  }
  __syncthreads();   // H1 visible; W2 chunk0 (issued at c=47) drained into buf0

  // ================= Layer 2: 32 chunks (K=256) =================
  #pragma unroll 2
  for (int c = 0; c < 32; ++c) {
    if (c < 31) issueW2(c + 1, (c + 1) & 1);
    else        issueW3(0, 0);               // (global chunk 80)&1==0
    gemmC(sH + c * 8, 256, sW + (c & 1) * 2048);
    __syncthreads();
  }

  { // L2 epilogue: acc+b2 -> sH (no relu)
    float4 b = *(const float4*)&se_b2[colBase];
    #pragma unroll
    for (int i = 0; i < 7; ++i) {
      float4 hv;
      hv.x = acc[i][0].x + b.x;
      hv.y = acc[i][0].y + b.y;
      hv.z = acc[i][1].x + b.z;
      hv.w = acc[i][1].y + b.w;
      *(float4*)&sH[(te * 7 + i) * 256 + colBase] = hv;
    }
    zero_acc();
  }
  __syncthreads();

  // ============ Layer 3: 32 chunks (K=256), cols = [pw1|vw1] ============
  #pragma unroll 2
  for (int c = 0; c < 32; ++c) {
    if (c < 31) issueW3(c + 1, (c + 1) & 1);
    gemmC(sH + c * 8, 256, sW + (c & 1) * 2048);
    __syncthreads();
  }

  { // L3 epilogue: relu(acc + [pb1|vb1]) -> sH
    float4 b = (ch == 0) ? *(const float4*)&pb1[tc * 4] : *(const float4*)&vb1[tc * 4];
    #pragma unroll
    for (int i = 0; i < 7; ++i) {
      float4 hv;
      hv.x = fmaxf(acc[i][0].x + b.x, 0.f);
      hv.y = fmaxf(acc[i][0].y + b.y, 0.f);
      hv.z = fmaxf(acc[i][1].x + b.z, 0.f);
      hv.w = fmaxf(acc[i][1].y + b.w, 0.f);
      *(float4*)&sH[(te * 7 + i) * 256 + colBase] = hv;
    }
  }
  __syncthreads();

  // ================= Layer 4: heads (two 128-dots per edge) =================
  if (t < 4 * 2 * TE) {        // 448 threads
    int lk   = t & 3;          // k quarter
    int d    = t >> 2;         // 0..111
    int head = (d >= TE);      // 0: policy, 1: value
    int edge = d - head * TE;  // 0..55
    int base = head * 128 + lk * 32;
    float p = 0.f;
    #pragma unroll
    for (int kk = 0; kk < 32; kk += 4) {
      float4 r4 = *(const float4*)&sH[edge * 256 + base + kk];
      float4 w4 = *(const float4*)&sW2[base + kk];
      p = fmaf(r4.x, w4.x, p);
      p = fmaf(r4.y, w4.y, p);
      p = fmaf(r4.z, w4.z, p);
      p = fmaf(r4.w, w4.w, p);
    }
    p += __shfl_xor(p, 1);
    p += __shfl_xor(p, 2);
    if (lk == 0) {
      int eg = e0 + edge;
      bool valid = eg < n_edges;
      if (head == 0) {
        float logit = p + pb2[0];
        if (valid) out[1 + eg] = (logit > 0.f) ? 1.f : 0.f;  // sigmoid(l)>0.5 <=> l>0
      } else {
        float term = 0.f;
        if (valid) {
          float z = p + vb2[0];
          float yv = (float)labels[sRow[edge]];
          term = fmaxf(z, 0.f) - z * yv + log1pf(expf(-fabsf(z)));
        }
        sLoss[edge] = term;
      }
    }
  }
  __syncthreads();
  if (t == 0) {
    float s = 0.f;
    #pragma unroll 4
    for (int i = 0; i < TE; ++i) s += sLoss[i];  // fixed order -> deterministic
    ws_partial[blockIdx.x] = s;
  }
}

__global__ void finalize_loss(const float* __restrict__ ws, float* __restrict__ out,
                              int n, double invE)
{
  __shared__ double sd[256];
  double a = 0.0;
  for (int i = threadIdx.x; i < n; i += 256) a += (double)ws[i];  // fixed order
  sd[threadIdx.x] = a;
  __syncthreads();
  for (int off = 128; off > 0; off >>= 1) {
    if ((int)threadIdx.x < off) sd[threadIdx.x] += sd[threadIdx.x + off];
    __syncthreads();
  }
  if (threadIdx.x == 0) out[0] = (float)(sd[0] * invE);
}

extern "C" void kernel_launch(void* const* d_in, const int* in_sizes, int n_in,
                              void* d_out, int out_size, void* d_ws, size_t ws_size,
                              hipStream_t stream) {
  const float* x      = (const float*)d_in[0];
  const int*   ei     = (const int*)  d_in[1];
  const float* gf     = (const float*)d_in[2];
  const int*   labels = (const int*)  d_in[3];
  const float* se_w1  = (const float*)d_in[4];
  const float* se_b1  = (const float*)d_in[5];
  const float* se_w2  = (const float*)d_in[6];
  const float* se_b2  = (const float*)d_in[7];
  const float* pw1    = (const float*)d_in[8];
  const float* pb1    = (const float*)d_in[9];
  const float* pw2    = (const float*)d_in[10];
  const float* pb2    = (const float*)d_in[11];
  const float* vw1    = (const float*)d_in[12];
  const float* vb1    = (const float*)d_in[13];
  const float* vw2    = (const float*)d_in[14];
  const float* vb2    = (const float*)d_in[15];

  int n_edges = in_sizes[1] / 2;
  int nblocks = (n_edges + TE - 1) / TE;
  float* out = (float*)d_out;
  float* ws  = (float*)d_ws;

  size_t shmem = SMEM_FLOATS * sizeof(float);  // 75520 B -> 2 blocks/CU
  (void)hipFuncSetAttribute((const void*)fused_edge_mlp,
                            hipFuncAttributeMaxDynamicSharedMemorySize, (int)shmem);

  fused_edge_mlp<<<dim3(nblocks), dim3(NTHREADS), shmem, stream>>>(
      x, ei, gf, labels,
      se_w1, se_b1, se_w2, se_b2,
      pw1, pb1, pw2, pb2,
      vw1, vb1, vw2, vb2,
      out, ws, n_edges);

  finalize_loss<<<dim3(1), dim3(256), 0, stream>>>(ws, out, nblocks, 1.0 / (double)n_edges);
}

// Round 9
// 2658.199 us; speedup vs baseline: 1.3745x; 1.0073x over previous
//
#include <hip/hip_runtime.h>
#include <cstddef>

#define TE 56          // edges per block -> acc 7x4 per thread
#define NTHREADS 512

typedef float v2f __attribute__((ext_vector_type(2)));

// v_pk_fma_f32 with op_sel broadcast of src0 (the A scalar):
//  PK_LO: both result halves use src0.lo  -> acc += a.lo * w
//  PK_HI: both result halves use src0.hi  -> acc += a.hi * w
// Exactly two IEEE f32 FMAs -> bitwise identical to scalar v_fma_f32 path.
// (r8 evidence: __builtin_elementwise_fma on v2f scalarizes - VALUBusy stayed 70.7%)
#define PK_LO(accv, av, wv) \
  asm("v_pk_fma_f32 %0, %1, %2, %0 op_sel:[0,0,0] op_sel_hi:[0,1,1]" \
      : "+v"(accv) : "v"(av), "v"(wv))
#define PK_HI(accv, av, wv) \
  asm("v_pk_fma_f32 %0, %1, %2, %0 op_sel:[1,0,0] op_sel_hi:[1,1,1]" \
      : "+v"(accv) : "v"(av), "v"(wv))

// LDS layout (float offsets) — total 75520 B (proven 2 blocks/CU footprint)
#define SH_OFF    0                    // [56][256] = 14336 floats; first 7168 alias A tile [56][128]
#define SW_OFF    14336                // W double-buffer [2][8][256] = 4096 floats
#define SW2_OFF   (SW_OFF + 4096)      // 256 floats: [pw2 | vw2]
#define SLOSS_OFF (SW2_OFF + 256)      // 64 floats (56 used)
#define SROW_OFF  (SLOSS_OFF + 64)     // 64 ints
#define SCOL_OFF  (SROW_OFF + 64)      // 64 ints
#define SMEM_FLOATS (SCOL_OFF + 64)    // 18880 floats = 75520 B

// Occupancy model (r1-r7): waves/SIMD = floor(256/VGPR); VGPR<=64 mandatory for
// 2 blocks/CU (46% occ). Staging via global_load_lds keeps reg need under the cap.
__device__ __forceinline__ void gld16(const float* g, float* l) {
  __builtin_amdgcn_global_load_lds(
      (const __attribute__((address_space(1))) void*)g,
      (__attribute__((address_space(3))) void*)l, 16, 0, 0);
}

__global__ __launch_bounds__(NTHREADS, 4)
void fused_edge_mlp(
    const float* __restrict__ x,
    const int*   __restrict__ edge_index,
    const float* __restrict__ gf,
    const int*   __restrict__ labels,
    const float* __restrict__ se_w1, const float* __restrict__ se_b1,
    const float* __restrict__ se_w2, const float* __restrict__ se_b2,
    const float* __restrict__ pw1,  const float* __restrict__ pb1,
    const float* __restrict__ pw2,  const float* __restrict__ pb2,
    const float* __restrict__ vw1,  const float* __restrict__ vb1,
    const float* __restrict__ vw2,  const float* __restrict__ vb2,
    float* __restrict__ out,        // out[0]=loss (finalize), out[1..E]=actions
    float* __restrict__ ws_partial,
    int n_edges)
{
  extern __shared__ float smem[];
  float* sH    = smem + SH_OFF;
  float* sA    = smem + SH_OFF;     // alias: A tile live only during L1 chunks
  float* sW    = smem + SW_OFF;     // [2][8][256]
  float* sW2   = smem + SW2_OFF;
  float* sLoss = smem + SLOSS_OFF;
  int*   sRow  = (int*)(smem + SROW_OFF);
  int*   sCol  = (int*)(smem + SCOL_OFF);

  const int t  = threadIdx.x;
  const int e0 = blockIdx.x * TE;

  // register tile: 7 edges x 4 cols per thread over [56 x 256]
  const int tc  = t & 31;
  const int teh = t >> 5;
  const int te  = teh & 7;          // edge group: rows te*7 .. te*7+6
  const int ch  = teh >> 3;
  const int colBase = ch * 128 + tc * 4;

  // W-chunk staging slot: thread t stages float4 #t of an [8][256] chunk
  const int wr  = t >> 6;           // = wave id: LDS dest is wave-uniform + lane*16
  const int wc4 = t & 63;

  // ---- prologue small stages ----
  if (t < TE) {
    int eg = e0 + t;
    sRow[t] = (eg < n_edges) ? edge_index[eg] : 0;
  } else if (t < 2 * TE) {
    int eg = e0 + (t - TE);
    sCol[t - TE] = (eg < n_edges) ? edge_index[(size_t)n_edges + eg] : 0;
  } else if (t >= 128 && t < 384) {
    int c = t - 128;
    sW2[c] = (c < 128) ? pw2[c] : vw2[c - 128];
  }

  v2f acc[7][2];   // [edge][col-pair]: cols colBase+{0,1} and colBase+{2,3}
  auto zero_acc = [&]() {
    #pragma unroll
    for (int i = 0; i < 7; ++i) {
      acc[i][0] = v2f{0.f, 0.f};
      acc[i][1] = v2f{0.f, 0.f};
    }
  };

  // async W-chunk stagers: one global_load_lds dwordx4 per thread
  auto issueW1 = [&](int c, int b) {
    gld16(&se_w1[((size_t)(c * 8 + wr)) * 256 + wc4 * 4], &sW[b * 2048 + t * 4]);
  };
  auto issueW2 = [&](int c, int b) {
    gld16(&se_w2[((size_t)(c * 8 + wr)) * 256 + wc4 * 4], &sW[b * 2048 + t * 4]);
  };
  auto issueW3 = [&](int c, int b) {
    int row = c * 8 + wr;
    const float* src = (wc4 < 32) ? &pw1[(size_t)row * 128 + wc4 * 4]
                                  : &vw1[(size_t)row * 128 + (wc4 - 32) * 4];
    gld16(src, &sW[b * 2048 + t * 4]);
  };

  // async A-tile gather: [56][128] = 1792 float4 (per-lane gathered source ok;
  // LDS dest linear: uniform + lane*16)
  auto stageA_issue = [&](int seg) {
    const float* src = (seg == 2) ? gf : x;
    const int*   idx = (seg == 0) ? sRow : sCol;
    #pragma unroll
    for (int j = 0; j < 3; ++j) {
      int i4 = t + j * NTHREADS;
      int r = i4 >> 5, c4 = i4 & 31;
      gld16(&src[(size_t)idx[r] * 128 + c4 * 4], &sA[i4 * 4]);
    }
    if (t < 256) {
      int i4 = t + 3 * NTHREADS;
      int r = i4 >> 5, c4 = i4 & 31;
      gld16(&src[(size_t)idx[r] * 128 + c4 * 4], &sA[i4 * 4]);
    }
  };

  // acc += A[56 x 8](stride LDA) @ Wb[8][256], this thread's 7x4 sub-tile.
  // Inner op: v_pk_fma_f32 with op_sel A-broadcast -> 8 issues per (k4,i)
  // instead of 16 scalar fma. Pairs (av.x,av.y)/(av.z,av.w) stay register
  // sub-pairs of the b128 load quads.
  auto gemmC = [&](const float* Ak, const int LDA, const float* Wb) {
    #pragma unroll
    for (int k4 = 0; k4 < 2; ++k4) {
      v2f w[4][2];
      #pragma unroll
      for (int dk = 0; dk < 4; ++dk) {
        float4 wv = *(const float4*)&Wb[(k4 * 4 + dk) * 256 + colBase];
        w[dk][0] = v2f{wv.x, wv.y};
        w[dk][1] = v2f{wv.z, wv.w};
      }
      #pragma unroll
      for (int i = 0; i < 7; ++i) {
        float4 av = *(const float4*)&Ak[(te * 7 + i) * LDA + k4 * 4];
        v2f pa01 = v2f{av.x, av.y};
        v2f pa23 = v2f{av.z, av.w};
        PK_LO(acc[i][0], pa01, w[0][0]);
        PK_LO(acc[i][1], pa01, w[0][1]);
        PK_HI(acc[i][0], pa01, w[1][0]);
        PK_HI(acc[i][1], pa01, w[1][1]);
        PK_LO(acc[i][0], pa23, w[2][0]);
        PK_LO(acc[i][1], pa23, w[2][1]);
        PK_HI(acc[i][0], pa23, w[3][0]);
        PK_HI(acc[i][1], pa23, w[3][1]);
      }
    }
  };

  // ---- prologue: W0 + A seg0 in flight ----
  issueW1(0, 0);
  __syncthreads();              // sRow/sCol visible
  stageA_issue(0);
  __syncthreads();              // A seg0 + W0 ready

  zero_acc();

  // ================= Layer 1: 48 chunks (K=384), W dbuf, 1 barrier/chunk ==========
  #pragma unroll 2
  for (int c = 0; c < 48; ++c) {
    bool segb = (c == 16) | (c == 32);
    if (segb) stageA_issue(c >> 4);          // next A segment (prev fully read)
    if (c < 47) issueW1(c + 1, (c + 1) & 1);
    else        issueW2(0, 0);               // cross-layer prefetch (48&1==0)
    if (segb) __syncthreads();               // drain new A before using it
    gemmC(sA + (c & 15) * 8, 128, sW + (c & 1) * 2048);
    __syncthreads();                         // W(c+1)/A drained; buf[c&1] free
  }

  { // L1 epilogue: relu(acc+b1) -> sH (overwrites sA alias)
    float4 b = *(const float4*)&se_b1[colBase];
    #pragma unroll
    for (int i = 0; i < 7; ++i) {
      float4 hv;
      hv.x = fmaxf(acc[i][0].x + b.x, 0.f);
      hv.y = fmaxf(acc[i][0].y + b.y, 0.f);
      hv.z = fmaxf(acc[i][1].x + b.z, 0.f);
      hv.w = fmaxf(acc[i][1].y + b.w, 0.f);
      *(float4*)&sH[(te * 7 + i) * 256 + colBase] = hv;
    }
    zero_acc();
  }
  __syncthreads();   // H1 visible; W2 chunk0 (issued at c=47) drained into buf0

  // ================= Layer 2: 32 chunks (K=256) =================
  #pragma unroll 2
  for (int c = 0; c < 32; ++c) {
    if (c < 31) issueW2(c + 1, (c + 1) & 1);
    else        issueW3(0, 0);               // (global chunk 80)&1==0
    gemmC(sH + c * 8, 256, sW + (c & 1) * 2048);
    __syncthreads();
  }

  { // L2 epilogue: acc+b2 -> sH (no relu)
    float4 b = *(const float4*)&se_b2[colBase];
    #pragma unroll
    for (int i = 0; i < 7; ++i) {
      float4 hv;
      hv.x = acc[i][0].x + b.x;
      hv.y = acc[i][0].y + b.y;
      hv.z = acc[i][1].x + b.z;
      hv.w = acc[i][1].y + b.w;
      *(float4*)&sH[(te * 7 + i) * 256 + colBase] = hv;
    }
    zero_acc();
  }
  __syncthreads();

  // ============ Layer 3: 32 chunks (K=256), cols = [pw1|vw1] ============
  #pragma unroll 2
  for (int c = 0; c < 32; ++c) {
    if (c < 31) issueW3(c + 1, (c + 1) & 1);
    gemmC(sH + c * 8, 256, sW + (c & 1) * 2048);
    __syncthreads();
  }

  { // L3 epilogue: relu(acc + [pb1|vb1]) -> sH
    float4 b = (ch == 0) ? *(const float4*)&pb1[tc * 4] : *(const float4*)&vb1[tc * 4];
    #pragma unroll
    for (int i = 0; i < 7; ++i) {
      float4 hv;
      hv.x = fmaxf(acc[i][0].x + b.x, 0.f);
      hv.y = fmaxf(acc[i][0].y + b.y, 0.f);
      hv.z = fmaxf(acc[i][1].x + b.z, 0.f);
      hv.w = fmaxf(acc[i][1].y + b.w, 0.f);
      *(float4*)&sH[(te * 7 + i) * 256 + colBase] = hv;
    }
  }
  __syncthreads();

  // ================= Layer 4: heads (two 128-dots per edge) =================
  if (t < 4 * 2 * TE) {        // 448 threads
    int lk   = t & 3;          // k quarter
    int d    = t >> 2;         // 0..111
    int head = (d >= TE);      // 0: policy, 1: value
    int edge = d - head * TE;  // 0..55
    int base = head * 128 + lk * 32;
    float p = 0.f;
    #pragma unroll
    for (int kk = 0; kk < 32; kk += 4) {
      float4 r4 = *(const float4*)&sH[edge * 256 + base + kk];
      float4 w4 = *(const float4*)&sW2[base + kk];
      p = fmaf(r4.x, w4.x, p);
      p = fmaf(r4.y, w4.y, p);
      p = fmaf(r4.z, w4.z, p);
      p = fmaf(r4.w, w4.w, p);
    }
    p += __shfl_xor(p, 1);
    p += __shfl_xor(p, 2);
    if (lk == 0) {
      int eg = e0 + edge;
      bool valid = eg < n_edges;
      if (head == 0) {
        float logit = p + pb2[0];
        if (valid) out[1 + eg] = (logit > 0.f) ? 1.f : 0.f;  // sigmoid(l)>0.5 <=> l>0
      } else {
        float term = 0.f;
        if (valid) {
          float z = p + vb2[0];
          float yv = (float)labels[sRow[edge]];
          term = fmaxf(z, 0.f) - z * yv + log1pf(expf(-fabsf(z)));
        }
        sLoss[edge] = term;
      }
    }
  }
  __syncthreads();
  if (t == 0) {
    float s = 0.f;
    #pragma unroll 4
    for (int i = 0; i < TE; ++i) s += sLoss[i];  // fixed order -> deterministic
    ws_partial[blockIdx.x] = s;
  }
}

__global__ void finalize_loss(const float* __restrict__ ws, float* __restrict__ out,
                              int n, double invE)
{
  __shared__ double sd[256];
  double a = 0.0;
  for (int i = threadIdx.x; i < n; i += 256) a += (double)ws[i];  // fixed order
  sd[threadIdx.x] = a;
  __syncthreads();
  for (int off = 128; off > 0; off >>= 1) {
    if ((int)threadIdx.x < off) sd[threadIdx.x] += sd[threadIdx.x + off];
    __syncthreads();
  }
  if (threadIdx.x == 0) out[0] = (float)(sd[0] * invE);
}

extern "C" void kernel_launch(void* const* d_in, const int* in_sizes, int n_in,
                              void* d_out, int out_size, void* d_ws, size_t ws_size,
                              hipStream_t stream) {
  const float* x      = (const float*)d_in[0];
  const int*   ei     = (const int*)  d_in[1];
  const float* gf     = (const float*)d_in[2];
  const int*   labels = (const int*)  d_in[3];
  const float* se_w1  = (const float*)d_in[4];
  const float* se_b1  = (const float*)d_in[5];
  const float* se_w2  = (const float*)d_in[6];
  const float* se_b2  = (const float*)d_in[7];
  const float* pw1    = (const float*)d_in[8];
  const float* pb1    = (const float*)d_in[9];
  const float* pw2    = (const float*)d_in[10];
  const float* pb2    = (const float*)d_in[11];
  const float* vw1    = (const float*)d_in[12];
  const float* vb1    = (const float*)d_in[13];
  const float* vw2    = (const float*)d_in[14];
  const float* vb2    = (const float*)d_in[15];

  int n_edges = in_sizes[1] / 2;
  int nblocks = (n_edges + TE - 1) / TE;
  float* out = (float*)d_out;
  float* ws  = (float*)d_ws;

  size_t shmem = SMEM_FLOATS * sizeof(float);  // 75520 B -> 2 blocks/CU
  (void)hipFuncSetAttribute((const void*)fused_edge_mlp,
                            hipFuncAttributeMaxDynamicSharedMemorySize, (int)shmem);

  fused_edge_mlp<<<dim3(nblocks), dim3(NTHREADS), shmem, stream>>>(
      x, ei, gf, labels,
      se_w1, se_b1, se_w2, se_b2,
      pw1, pb1, pw2, pb2,
      vw1, vb1, vw2, vb2,
      out, ws, n_edges);

  finalize_loss<<<dim3(1), dim3(256), 0, stream>>>(ws, out, nblocks, 1.0 / (double)n_edges);
}

// Round 10
// 2596.461 us; speedup vs baseline: 1.4072x; 1.0238x over previous
//
#include <hip/hip_runtime.h>
#include <cstddef>

#define TE 56          // edges per block -> acc 7x4 per thread
#define NTHREADS 512

typedef float v2f __attribute__((ext_vector_type(2)));

// v_pk_fma_f32 with op_sel broadcast of src0 (the A scalar):
//  PK_LO: both result halves use src0.lo  -> acc += a.lo * w
//  PK_HI: both result halves use src0.hi  -> acc += a.hi * w
// Exactly two IEEE f32 FMAs -> bitwise identical to scalar v_fma_f32 path.
// (r9 evidence: emitted for real — VGPR 64->44, spill 253MB->2.5MB, VALUBusy 70.7->63)
#define PK_LO(accv, av, wv) \
  asm("v_pk_fma_f32 %0, %1, %2, %0 op_sel:[0,0,0] op_sel_hi:[0,1,1]" \
      : "+v"(accv) : "v"(av), "v"(wv))
#define PK_HI(accv, av, wv) \
  asm("v_pk_fma_f32 %0, %1, %2, %0 op_sel:[1,0,0] op_sel_hi:[1,1,1]" \
      : "+v"(accv) : "v"(av), "v"(wv))

// LDS layout (float offsets) — total 75520 B (proven 2 blocks/CU footprint)
// sH [56][256] doubles as the A double-buffer during L1:
//   Abuf0 = smem[0..7167], Abuf1 = smem[7168..14335]  (each [56][128])
#define SH_OFF    0
#define SW_OFF    14336                // W double-buffer [2][8][256] = 4096 floats
#define SW2_OFF   (SW_OFF + 4096)      // 256 floats: [pw2 | vw2]
#define SLOSS_OFF (SW2_OFF + 256)      // 64 floats (56 used)
#define SROW_OFF  (SLOSS_OFF + 64)     // 64 ints
#define SCOL_OFF  (SROW_OFF + 64)      // 64 ints
#define SMEM_FLOATS (SCOL_OFF + 64)    // 18880 floats = 75520 B

// Occupancy model (r1-r9): waves/SIMD = floor(256/VGPR); VGPR<=64 mandatory for
// 2 blocks/CU (46% occ). Staging via global_load_lds keeps reg need at 44.
__device__ __forceinline__ void gld16(const float* g, float* l) {
  __builtin_amdgcn_global_load_lds(
      (const __attribute__((address_space(1))) void*)g,
      (__attribute__((address_space(3))) void*)l, 16, 0, 0);
}

__global__ __launch_bounds__(NTHREADS, 4)
void fused_edge_mlp(
    const float* __restrict__ x,
    const int*   __restrict__ edge_index,
    const float* __restrict__ gf,
    const int*   __restrict__ labels,
    const float* __restrict__ se_w1, const float* __restrict__ se_b1,
    const float* __restrict__ se_w2, const float* __restrict__ se_b2,
    const float* __restrict__ pw1,  const float* __restrict__ pb1,
    const float* __restrict__ pw2,  const float* __restrict__ pb2,
    const float* __restrict__ vw1,  const float* __restrict__ vb1,
    const float* __restrict__ vw2,  const float* __restrict__ vb2,
    float* __restrict__ out,        // out[0]=loss (finalize), out[1..E]=actions
    float* __restrict__ ws_partial,
    int n_edges)
{
  extern __shared__ float smem[];
  float* sH    = smem + SH_OFF;
  float* sA    = smem + SH_OFF;     // A dbuf aliases sH during L1
  float* sW    = smem + SW_OFF;     // [2][8][256]
  float* sW2   = smem + SW2_OFF;
  float* sLoss = smem + SLOSS_OFF;
  int*   sRow  = (int*)(smem + SROW_OFF);
  int*   sCol  = (int*)(smem + SCOL_OFF);

  const int t  = threadIdx.x;
  const int e0 = blockIdx.x * TE;

  // register tile: 7 edges x 4 cols per thread over [56 x 256]
  const int tc  = t & 31;
  const int teh = t >> 5;
  const int te  = teh & 7;          // edge group: rows te*7 .. te*7+6
  const int ch  = teh >> 3;
  const int colBase = ch * 128 + tc * 4;

  // W-chunk staging slot: thread t stages float4 #t of an [8][256] chunk
  const int wr  = t >> 6;           // = wave id: LDS dest is wave-uniform + lane*16
  const int wc4 = t & 63;

  // ---- prologue small stages ----
  if (t < TE) {
    int eg = e0 + t;
    sRow[t] = (eg < n_edges) ? edge_index[eg] : 0;
  } else if (t < 2 * TE) {
    int eg = e0 + (t - TE);
    sCol[t - TE] = (eg < n_edges) ? edge_index[(size_t)n_edges + eg] : 0;
  } else if (t >= 128 && t < 384) {
    int c = t - 128;
    sW2[c] = (c < 128) ? pw2[c] : vw2[c - 128];
  }

  v2f acc[7][2];   // [edge][col-pair]
  auto zero_acc = [&]() {
    #pragma unroll
    for (int i = 0; i < 7; ++i) {
      acc[i][0] = v2f{0.f, 0.f};
      acc[i][1] = v2f{0.f, 0.f};
    }
  };

  // async W-chunk stagers: one global_load_lds dwordx4 per thread
  auto issueW1 = [&](int c, int b) {
    gld16(&se_w1[((size_t)(c * 8 + wr)) * 256 + wc4 * 4], &sW[b * 2048 + t * 4]);
  };
  auto issueW2 = [&](int c, int b) {
    gld16(&se_w2[((size_t)(c * 8 + wr)) * 256 + wc4 * 4], &sW[b * 2048 + t * 4]);
  };
  auto issueW3 = [&](int c, int b) {
    int row = c * 8 + wr;
    const float* src = (wc4 < 32) ? &pw1[(size_t)row * 128 + wc4 * 4]
                                  : &vw1[(size_t)row * 128 + (wc4 - 32) * 4];
    gld16(src, &sW[b * 2048 + t * 4]);
  };

  // async A-tile gather into buffer b: [56][128] = 1792 float4
  auto stageA_issue = [&](int seg, int b) {
    const float* src = (seg == 2) ? gf : x;
    const int*   idx = (seg == 0) ? sRow : sCol;
    float* dst = sA + b * 7168;
    #pragma unroll
    for (int j = 0; j < 3; ++j) {
      int i4 = t + j * NTHREADS;
      int r = i4 >> 5, c4 = i4 & 31;
      gld16(&src[(size_t)idx[r] * 128 + c4 * 4], &dst[i4 * 4]);
    }
    if (t < 256) {
      int i4 = t + 3 * NTHREADS;
      int r = i4 >> 5, c4 = i4 & 31;
      gld16(&src[(size_t)idx[r] * 128 + c4 * 4], &dst[i4 * 4]);
    }
  };

  // acc += A[56 x 8](stride LDA) @ Wb[8][256]: 112 v_pk_fma_f32 per call
  auto gemmC = [&](const float* Ak, const int LDA, const float* Wb) {
    #pragma unroll
    for (int k4 = 0; k4 < 2; ++k4) {
      v2f w[4][2];
      #pragma unroll
      for (int dk = 0; dk < 4; ++dk) {
        float4 wv = *(const float4*)&Wb[(k4 * 4 + dk) * 256 + colBase];
        w[dk][0] = v2f{wv.x, wv.y};
        w[dk][1] = v2f{wv.z, wv.w};
      }
      #pragma unroll
      for (int i = 0; i < 7; ++i) {
        float4 av = *(const float4*)&Ak[(te * 7 + i) * LDA + k4 * 4];
        v2f pa01 = v2f{av.x, av.y};
        v2f pa23 = v2f{av.z, av.w};
        PK_LO(acc[i][0], pa01, w[0][0]);
        PK_LO(acc[i][1], pa01, w[0][1]);
        PK_HI(acc[i][0], pa01, w[1][0]);
        PK_HI(acc[i][1], pa01, w[1][1]);
        PK_LO(acc[i][0], pa23, w[2][0]);
        PK_LO(acc[i][1], pa23, w[2][1]);
        PK_HI(acc[i][0], pa23, w[3][0]);
        PK_HI(acc[i][1], pa23, w[3][1]);
      }
    }
  };

  // ---- prologue: W0 + A seg0 in flight ----
  issueW1(0, 0);
  __syncthreads();              // sRow/sCol visible
  stageA_issue(0, 0);
  __syncthreads();              // A seg0 + W0 ready

  zero_acc();

  // ===== Layer 1: 3 segments x 16 chunks; A double-buffered (issue at seg top,
  // ~16 gemms of DMA cover vs 0 in r9's synchronous boundary) =====
  for (int seg = 0; seg < 3; ++seg) {
    const float* Ab = sA + (seg & 1) * 7168;
    if (seg < 2) stageA_issue(seg + 1, (seg + 1) & 1);   // prev buf freed at seg-1's last barrier
    #pragma unroll 4
    for (int kc = 0; kc < 16; ++kc) {
      int c = seg * 16 + kc;
      if (c < 47) issueW1(c + 1, (c + 1) & 1);
      else        issueW2(0, 0);               // cross-layer prefetch (48&1==0)
      gemmC(Ab + kc * 8, 128, sW + (c & 1) * 2048);
      __syncthreads();                         // W(c+1)+A drained; buf[c&1] free
    }
  }

  { // L1 epilogue: relu(acc+b1) -> sH (overwrites A dbuf; all A reads done)
    float4 b = *(const float4*)&se_b1[colBase];
    #pragma unroll
    for (int i = 0; i < 7; ++i) {
      float4 hv;
      hv.x = fmaxf(acc[i][0].x + b.x, 0.f);
      hv.y = fmaxf(acc[i][0].y + b.y, 0.f);
      hv.z = fmaxf(acc[i][1].x + b.z, 0.f);
      hv.w = fmaxf(acc[i][1].y + b.w, 0.f);
      *(float4*)&sH[(te * 7 + i) * 256 + colBase] = hv;
    }
    zero_acc();
  }
  __syncthreads();   // H1 visible; W2 chunk0 (issued at c=47) already drained

  // ================= Layer 2: 32 chunks (K=256) =================
  #pragma unroll 4
  for (int c = 0; c < 32; ++c) {
    if (c < 31) issueW2(c + 1, (c + 1) & 1);
    else        issueW3(0, 0);               // (global chunk 80)&1==0
    gemmC(sH + c * 8, 256, sW + (c & 1) * 2048);
    __syncthreads();
  }

  { // L2 epilogue: acc+b2 -> sH (no relu)
    float4 b = *(const float4*)&se_b2[colBase];
    #pragma unroll
    for (int i = 0; i < 7; ++i) {
      float4 hv;
      hv.x = acc[i][0].x + b.x;
      hv.y = acc[i][0].y + b.y;
      hv.z = acc[i][1].x + b.z;
      hv.w = acc[i][1].y + b.w;
      *(float4*)&sH[(te * 7 + i) * 256 + colBase] = hv;
    }
    zero_acc();
  }
  __syncthreads();

  // ============ Layer 3: 32 chunks (K=256), cols = [pw1|vw1] ============
  #pragma unroll 4
  for (int c = 0; c < 32; ++c) {
    if (c < 31) issueW3(c + 1, (c + 1) & 1);
    gemmC(sH + c * 8, 256, sW + (c & 1) * 2048);
    __syncthreads();
  }

  { // L3 epilogue: relu(acc + [pb1|vb1]) -> sH
    float4 b = (ch == 0) ? *(const float4*)&pb1[tc * 4] : *(const float4*)&vb1[tc * 4];
    #pragma unroll
    for (int i = 0; i < 7; ++i) {
      float4 hv;
      hv.x = fmaxf(acc[i][0].x + b.x, 0.f);
      hv.y = fmaxf(acc[i][0].y + b.y, 0.f);
      hv.z = fmaxf(acc[i][1].x + b.z, 0.f);
      hv.w = fmaxf(acc[i][1].y + b.w, 0.f);
      *(float4*)&sH[(te * 7 + i) * 256 + colBase] = hv;
    }
  }
  __syncthreads();

  // ================= Layer 4: heads (two 128-dots per edge) =================
  if (t < 4 * 2 * TE) {        // 448 threads
    int lk   = t & 3;          // k quarter
    int d    = t >> 2;         // 0..111
    int head = (d >= TE);      // 0: policy, 1: value
    int edge = d - head * TE;  // 0..55
    int base = head * 128 + lk * 32;
    float p = 0.f;
    #pragma unroll
    for (int kk = 0; kk < 32; kk += 4) {
      float4 r4 = *(const float4*)&sH[edge * 256 + base + kk];
      float4 w4 = *(const float4*)&sW2[base + kk];
      p = fmaf(r4.x, w4.x, p);
      p = fmaf(r4.y, w4.y, p);
      p = fmaf(r4.z, w4.z, p);
      p = fmaf(r4.w, w4.w, p);
    }
    p += __shfl_xor(p, 1);
    p += __shfl_xor(p, 2);
    if (lk == 0) {
      int eg = e0 + edge;
      bool valid = eg < n_edges;
      if (head == 0) {
        float logit = p + pb2[0];
        if (valid) out[1 + eg] = (logit > 0.f) ? 1.f : 0.f;  // sigmoid(l)>0.5 <=> l>0
      } else {
        float term = 0.f;
        if (valid) {
          float z = p + vb2[0];
          float yv = (float)labels[sRow[edge]];
          term = fmaxf(z, 0.f) - z * yv + log1pf(expf(-fabsf(z)));
        }
        sLoss[edge] = term;
      }
    }
  }
  __syncthreads();
  if (t == 0) {
    float s = 0.f;
    #pragma unroll 4
    for (int i = 0; i < TE; ++i) s += sLoss[i];  // fixed order -> deterministic
    ws_partial[blockIdx.x] = s;
  }
}

__global__ void finalize_loss(const float* __restrict__ ws, float* __restrict__ out,
                              int n, double invE)
{
  __shared__ double sd[256];
  double a = 0.0;
  for (int i = threadIdx.x; i < n; i += 256) a += (double)ws[i];  // fixed order
  sd[threadIdx.x] = a;
  __syncthreads();
  for (int off = 128; off > 0; off >>= 1) {
    if ((int)threadIdx.x < off) sd[threadIdx.x] += sd[threadIdx.x + off];
    __syncthreads();
  }
  if (threadIdx.x == 0) out[0] = (float)(sd[0] * invE);
}

extern "C" void kernel_launch(void* const* d_in, const int* in_sizes, int n_in,
                              void* d_out, int out_size, void* d_ws, size_t ws_size,
                              hipStream_t stream) {
  const float* x      = (const float*)d_in[0];
  const int*   ei     = (const int*)  d_in[1];
  const float* gf     = (const float*)d_in[2];
  const int*   labels = (const int*)  d_in[3];
  const float* se_w1  = (const float*)d_in[4];
  const float* se_b1  = (const float*)d_in[5];
  const float* se_w2  = (const float*)d_in[6];
  const float* se_b2  = (const float*)d_in[7];
  const float* pw1    = (const float*)d_in[8];
  const float* pb1    = (const float*)d_in[9];
  const float* pw2    = (const float*)d_in[10];
  const float* pb2    = (const float*)d_in[11];
  const float* vw1    = (const float*)d_in[12];
  const float* vb1    = (const float*)d_in[13];
  const float* vw2    = (const float*)d_in[14];
  const float* vb2    = (const float*)d_in[15];

  int n_edges = in_sizes[1] / 2;
  int nblocks = (n_edges + TE - 1) / TE;
  float* out = (float*)d_out;
  float* ws  = (float*)d_ws;

  size_t shmem = SMEM_FLOATS * sizeof(float);  // 75520 B -> 2 blocks/CU
  (void)hipFuncSetAttribute((const void*)fused_edge_mlp,
                            hipFuncAttributeMaxDynamicSharedMemorySize, (int)shmem);

  fused_edge_mlp<<<dim3(nblocks), dim3(NTHREADS), shmem, stream>>>(
      x, ei, gf, labels,
      se_w1, se_b1, se_w2, se_b2,
      pw1, pb1, pw2, pb2,
      vw1, vb1, vw2, vb2,
      out, ws, n_edges);

  finalize_loss<<<dim3(1), dim3(256), 0, stream>>>(ws, out, nblocks, 1.0 / (double)n_edges);
}

// Round 11
// 2540.066 us; speedup vs baseline: 1.4385x; 1.0222x over previous
//
#include <hip/hip_runtime.h>
#include <cstddef>

#define TE 64          // edges per block -> acc 8x4 per thread
#define NTHREADS 512

typedef float v2f __attribute__((ext_vector_type(2)));

// v_pk_fma_f32 with op_sel broadcast of src0 (the A scalar):
//  PK_LO: both result halves use src0.lo -> acc += a.lo * w
//  PK_HI: both result halves use src0.hi -> acc += a.hi * w
// Exactly two IEEE f32 FMAs -> bitwise identical to scalar v_fma_f32 path.
#define PK_LO(accv, av, wv) \
  asm("v_pk_fma_f32 %0, %1, %2, %0 op_sel:[0,0,0] op_sel_hi:[0,1,1]" \
      : "+v"(accv) : "v"(av), "v"(wv))
#define PK_HI(accv, av, wv) \
  asm("v_pk_fma_f32 %0, %1, %2, %0 op_sel:[1,0,0] op_sel_hi:[1,1,1]" \
      : "+v"(accv) : "v"(av), "v"(wv))

// LDS layout: EXACTLY 81920 B = 160 KiB / 2 -> 2 blocks/CU uses the full pool.
//   smem[0..16383]      H tile [64][256] fp32; during L1 aliased as A dbuf
//                       (buf0 = [0..8191], buf1 = [8192..16383], each [64][128])
//   smem[16384..20479]  W double-buffer [2][8][256]
//   sLoss aliases smem[16384..] after the last chunk (W dead by then).
// All former extras evicted from LDS (r10 had +1.3KB -> would break the fit):
//   sRow/sCol -> edge_index re-loaded from L1 at stage time
//   sW2       -> L4 reads pw2/vw2 from global (L2-hot, 1KB)
#define SW_OFF 16384
#define SMEM_FLOATS 20480   // 81920 B

// Occupancy model (r1-r10): waves/SIMD = floor(256/VGPR); VGPR<=64 mandatory
// for 2 blocks/CU. pk_fma + global_load_lds staging keeps natural need ~52-56.
__device__ __forceinline__ void gld16(const float* g, float* l) {
  __builtin_amdgcn_global_load_lds(
      (const __attribute__((address_space(1))) void*)g,
      (__attribute__((address_space(3))) void*)l, 16, 0, 0);
}

__global__ __launch_bounds__(NTHREADS, 4)
void fused_edge_mlp(
    const float* __restrict__ x,
    const int*   __restrict__ edge_index,
    const float* __restrict__ gf,
    const int*   __restrict__ labels,
    const float* __restrict__ se_w1, const float* __restrict__ se_b1,
    const float* __restrict__ se_w2, const float* __restrict__ se_b2,
    const float* __restrict__ pw1,  const float* __restrict__ pb1,
    const float* __restrict__ pw2,  const float* __restrict__ pb2,
    const float* __restrict__ vw1,  const float* __restrict__ vb1,
    const float* __restrict__ vw2,  const float* __restrict__ vb2,
    float* __restrict__ out,        // out[0]=loss (finalize), out[1..E]=actions
    float* __restrict__ ws_partial,
    int n_edges)
{
  extern __shared__ float smem[];
  float* sH    = smem;
  float* sA    = smem;              // A dbuf aliases sH during L1
  float* sW    = smem + SW_OFF;     // [2][8][256]
  float* sLoss = smem + SW_OFF;     // valid only after last chunk

  const int t  = threadIdx.x;
  const int e0 = blockIdx.x * TE;

  // register tile: 8 edges x 4 cols per thread over [64 x 256]
  const int tc  = t & 31;
  const int teh = t >> 5;
  const int te  = teh & 7;          // edge group: rows te*8 .. te*8+7
  const int ch  = teh >> 3;
  const int colBase = ch * 128 + tc * 4;

  // W-chunk staging slot: thread t stages float4 #t of an [8][256] chunk
  const int wr  = t >> 6;           // LDS dest is wave-uniform + lane*16
  const int wc4 = t & 63;

  v2f acc[8][2];   // [edge][col-pair]
  auto zero_acc = [&]() {
    #pragma unroll
    for (int i = 0; i < 8; ++i) {
      acc[i][0] = v2f{0.f, 0.f};
      acc[i][1] = v2f{0.f, 0.f};
    }
  };

  // async W-chunk stagers: one global_load_lds dwordx4 per thread
  auto issueW1 = [&](int c, int b) {
    gld16(&se_w1[((size_t)(c * 8 + wr)) * 256 + wc4 * 4], &sW[b * 2048 + t * 4]);
  };
  auto issueW2 = [&](int c, int b) {
    gld16(&se_w2[((size_t)(c * 8 + wr)) * 256 + wc4 * 4], &sW[b * 2048 + t * 4]);
  };
  auto issueW3 = [&](int c, int b) {
    int row = c * 8 + wr;
    const float* src = (wc4 < 32) ? &pw1[(size_t)row * 128 + wc4 * 4]
                                  : &vw1[(size_t)row * 128 + (wc4 - 32) * 4];
    gld16(src, &sW[b * 2048 + t * 4]);
  };

  // async A-tile gather into buffer b: [64][128] = 2048 float4, 4/thread.
  // idx loaded straight from edge_index (L1-broadcast); no LDS copy needed.
  auto stageA_issue = [&](int seg, int b) {
    float* dst = sA + b * 8192;
    #pragma unroll
    for (int j = 0; j < 4; ++j) {
      int r  = (t >> 5) + j * 16;       // (t + j*512) >> 5
      int eg = e0 + r;
      bool v = eg < n_edges;
      int node;
      const float* src;
      if (seg == 0)      { node = v ? edge_index[eg] : 0;                   src = x;  }
      else if (seg == 1) { node = v ? edge_index[(size_t)n_edges + eg] : 0; src = x;  }
      else               { node = v ? edge_index[(size_t)n_edges + eg] : 0; src = gf; }
      gld16(&src[(size_t)node * 128 + tc * 4], &dst[(t + j * 512) * 4]);
    }
  };

  // acc += A[64 x 8](stride LDA) @ Wb[8][256]: 128 v_pk_fma_f32 per call
  auto gemmC = [&](const float* Ak, const int LDA, const float* Wb) {
    #pragma unroll
    for (int k4 = 0; k4 < 2; ++k4) {
      v2f w[4][2];
      #pragma unroll
      for (int dk = 0; dk < 4; ++dk) {
        float4 wv = *(const float4*)&Wb[(k4 * 4 + dk) * 256 + colBase];
        w[dk][0] = v2f{wv.x, wv.y};
        w[dk][1] = v2f{wv.z, wv.w};
      }
      #pragma unroll
      for (int i = 0; i < 8; ++i) {
        float4 av = *(const float4*)&Ak[(te * 8 + i) * LDA + k4 * 4];
        v2f pa01 = v2f{av.x, av.y};
        v2f pa23 = v2f{av.z, av.w};
        PK_LO(acc[i][0], pa01, w[0][0]);
        PK_LO(acc[i][1], pa01, w[0][1]);
        PK_HI(acc[i][0], pa01, w[1][0]);
        PK_HI(acc[i][1], pa01, w[1][1]);
        PK_LO(acc[i][0], pa23, w[2][0]);
        PK_LO(acc[i][1], pa23, w[2][1]);
        PK_HI(acc[i][0], pa23, w[3][0]);
        PK_HI(acc[i][1], pa23, w[3][1]);
      }
    }
  };

  // ---- prologue: W0 + A seg0 in flight ----
  issueW1(0, 0);
  stageA_issue(0, 0);
  __syncthreads();              // drains both (vmcnt(0) in syncthreads)

  zero_acc();

  // ===== Layer 1: 3 segments x 16 chunks; A double-buffered =====
  for (int seg = 0; seg < 3; ++seg) {
    const float* Ab = sA + (seg & 1) * 8192;
    if (seg < 2) stageA_issue(seg + 1, (seg + 1) & 1);   // prev buf freed at seg-1's last barrier
    #pragma unroll 4
    for (int kc = 0; kc < 16; ++kc) {
      int c = seg * 16 + kc;
      if (c < 47) issueW1(c + 1, (c + 1) & 1);
      else        issueW2(0, 0);               // cross-layer prefetch (48&1==0)
      gemmC(Ab + kc * 8, 128, sW + (c & 1) * 2048);
      __syncthreads();                         // W(c+1)+A drained; buf[c&1] free
    }
  }

  { // L1 epilogue: relu(acc+b1) -> sH (overwrites A dbuf; all A reads done)
    float4 b = *(const float4*)&se_b1[colBase];
    #pragma unroll
    for (int i = 0; i < 8; ++i) {
      float4 hv;
      hv.x = fmaxf(acc[i][0].x + b.x, 0.f);
      hv.y = fmaxf(acc[i][0].y + b.y, 0.f);
      hv.z = fmaxf(acc[i][1].x + b.z, 0.f);
      hv.w = fmaxf(acc[i][1].y + b.w, 0.f);
      *(float4*)&sH[(te * 8 + i) * 256 + colBase] = hv;
    }
    zero_acc();
  }
  __syncthreads();   // H1 visible; W2 chunk0 (issued at c=47) already drained

  // ================= Layer 2: 32 chunks (K=256) =================
  #pragma unroll 4
  for (int c = 0; c < 32; ++c) {
    if (c < 31) issueW2(c + 1, (c + 1) & 1);
    else        issueW3(0, 0);               // (global chunk 80)&1==0
    gemmC(sH + c * 8, 256, sW + (c & 1) * 2048);
    __syncthreads();
  }

  { // L2 epilogue: acc+b2 -> sH (no relu)
    float4 b = *(const float4*)&se_b2[colBase];
    #pragma unroll
    for (int i = 0; i < 8; ++i) {
      float4 hv;
      hv.x = acc[i][0].x + b.x;
      hv.y = acc[i][0].y + b.y;
      hv.z = acc[i][1].x + b.z;
      hv.w = acc[i][1].y + b.w;
      *(float4*)&sH[(te * 8 + i) * 256 + colBase] = hv;
    }
    zero_acc();
  }
  __syncthreads();

  // ============ Layer 3: 32 chunks (K=256), cols = [pw1|vw1] ============
  #pragma unroll 4
  for (int c = 0; c < 32; ++c) {
    if (c < 31) issueW3(c + 1, (c + 1) & 1);
    gemmC(sH + c * 8, 256, sW + (c & 1) * 2048);
    __syncthreads();
  }

  { // L3 epilogue: relu(acc + [pb1|vb1]) -> sH
    float4 b = (ch == 0) ? *(const float4*)&pb1[tc * 4] : *(const float4*)&vb1[tc * 4];
    #pragma unroll
    for (int i = 0; i < 8; ++i) {
      float4 hv;
      hv.x = fmaxf(acc[i][0].x + b.x, 0.f);
      hv.y = fmaxf(acc[i][0].y + b.y, 0.f);
      hv.z = fmaxf(acc[i][1].x + b.z, 0.f);
      hv.w = fmaxf(acc[i][1].y + b.w, 0.f);
      *(float4*)&sH[(te * 8 + i) * 256 + colBase] = hv;
    }
  }
  __syncthreads();   // also: W bufs now dead -> sLoss region valid

  // ================= Layer 4: heads (two 128-dots per edge) =================
  {
    int lk   = t & 3;          // k quarter
    int d    = t >> 2;         // 0..127
    int head = d >> 6;         // 0: policy, 1: value
    int edge = d & 63;         // 0..63
    const float* w2 = head ? vw2 : pw2;   // global, L2-hot (sW2 evicted from LDS)
    float p = 0.f;
    #pragma unroll
    for (int kk = 0; kk < 32; kk += 4) {
      float4 r4 = *(const float4*)&sH[edge * 256 + head * 128 + lk * 32 + kk];
      float4 w4 = *(const float4*)&w2[lk * 32 + kk];
      p = fmaf(r4.x, w4.x, p);
      p = fmaf(r4.y, w4.y, p);
      p = fmaf(r4.z, w4.z, p);
      p = fmaf(r4.w, w4.w, p);
    }
    p += __shfl_xor(p, 1);
    p += __shfl_xor(p, 2);
    if (lk == 0) {
      int eg = e0 + edge;
      bool valid = eg < n_edges;
      if (head == 0) {
        float logit = p + pb2[0];
        if (valid) out[1 + eg] = (logit > 0.f) ? 1.f : 0.f;  // sigmoid(l)>0.5 <=> l>0
      } else {
        float term = 0.f;
        if (valid) {
          float z = p + vb2[0];
          int srcn = edge_index[eg];               // row index (L1-hot)
          float yv = (float)labels[srcn];
          term = fmaxf(z, 0.f) - z * yv + log1pf(expf(-fabsf(z)));
        }
        sLoss[edge] = term;
      }
    }
  }
  __syncthreads();
  if (t == 0) {
    float s = 0.f;
    #pragma unroll 4
    for (int i = 0; i < TE; ++i) s += sLoss[i];  // fixed order -> deterministic
    ws_partial[blockIdx.x] = s;
  }
}

__global__ void finalize_loss(const float* __restrict__ ws, float* __restrict__ out,
                              int n, double invE)
{
  __shared__ double sd[256];
  double a = 0.0;
  for (int i = threadIdx.x; i < n; i += 256) a += (double)ws[i];  // fixed order
  sd[threadIdx.x] = a;
  __syncthreads();
  for (int off = 128; off > 0; off >>= 1) {
    if ((int)threadIdx.x < off) sd[threadIdx.x] += sd[threadIdx.x + off];
    __syncthreads();
  }
  if (threadIdx.x == 0) out[0] = (float)(sd[0] * invE);
}

extern "C" void kernel_launch(void* const* d_in, const int* in_sizes, int n_in,
                              void* d_out, int out_size, void* d_ws, size_t ws_size,
                              hipStream_t stream) {
  const float* x      = (const float*)d_in[0];
  const int*   ei     = (const int*)  d_in[1];
  const float* gf     = (const float*)d_in[2];
  const int*   labels = (const int*)  d_in[3];
  const float* se_w1  = (const float*)d_in[4];
  const float* se_b1  = (const float*)d_in[5];
  const float* se_w2  = (const float*)d_in[6];
  const float* se_b2  = (const float*)d_in[7];
  const float* pw1    = (const float*)d_in[8];
  const float* pb1    = (const float*)d_in[9];
  const float* pw2    = (const float*)d_in[10];
  const float* pb2    = (const float*)d_in[11];
  const float* vw1    = (const float*)d_in[12];
  const float* vb1    = (const float*)d_in[13];
  const float* vw2    = (const float*)d_in[14];
  const float* vb2    = (const float*)d_in[15];

  int n_edges = in_sizes[1] / 2;
  int nblocks = (n_edges + TE - 1) / TE;
  float* out = (float*)d_out;
  float* ws  = (float*)d_ws;

  size_t shmem = SMEM_FLOATS * sizeof(float);  // 81920 B exactly -> 2 blocks/CU
  (void)hipFuncSetAttribute((const void*)fused_edge_mlp,
                            hipFuncAttributeMaxDynamicSharedMemorySize, (int)shmem);

  fused_edge_mlp<<<dim3(nblocks), dim3(NTHREADS), shmem, stream>>>(
      x, ei, gf, labels,
      se_w1, se_b1, se_w2, se_b2,
      pw1, pb1, pw2, pb2,
      vw1, vb1, vw2, vb2,
      out, ws, n_edges);

  finalize_loss<<<dim3(1), dim3(256), 0, stream>>>(ws, out, nblocks, 1.0 / (double)n_edges);
}

// Round 12
// 2477.826 us; speedup vs baseline: 1.4746x; 1.0251x over previous
//
#include <hip/hip_runtime.h>
#include <cstddef>

#define TE 64          // edges per block -> acc 8x4 per thread
#define NTHREADS 512

typedef float v2f __attribute__((ext_vector_type(2)));
typedef float v4f __attribute__((ext_vector_type(4)));

// v_pk_fma_f32 with op_sel broadcast of src0 (the A scalar):
//  PK_LO: both result halves use src0.lo -> acc += a.lo * w
//  PK_HI: both result halves use src0.hi -> acc += a.hi * w
// Exactly two IEEE f32 FMAs -> bitwise identical to scalar v_fma_f32 path.
#define PK_LO(accv, av, wv) \
  asm("v_pk_fma_f32 %0, %1, %2, %0 op_sel:[0,0,0] op_sel_hi:[0,1,1]" \
      : "+v"(accv) : "v"(av), "v"(wv))
#define PK_HI(accv, av, wv) \
  asm("v_pk_fma_f32 %0, %1, %2, %0 op_sel:[1,0,0] op_sel_hi:[1,1,1]" \
      : "+v"(accv) : "v"(av), "v"(wv))

// LDS layout: EXACTLY 81920 B = 160 KiB / 2 -> 2 blocks/CU uses the full pool.
//   smem[0..16383]      H tile [64][256] fp32; during L1 aliased as A dbuf
//   smem[16384..20479]  W double-buffer [2][8][256]
//   sLoss aliases smem[16384..] after the last chunk (W dead by then).
#define SW_OFF 16384
#define SMEM_FLOATS 20480   // 81920 B

// Occupancy model (r1-r11): waves/SIMD = floor(256/VGPR); VGPR<=64 mandatory
// for 2 blocks/CU (45% occ). r11: VGPR 56. This round adds ~4 live regs
// (2-row interleave) -> budget ~60, still under the cliff.
__device__ __forceinline__ void gld16(const float* g, float* l) {
  __builtin_amdgcn_global_load_lds(
      (const __attribute__((address_space(1))) void*)g,
      (__attribute__((address_space(3))) void*)l, 16, 0, 0);
}

__global__ __launch_bounds__(NTHREADS, 4)
void fused_edge_mlp(
    const float* __restrict__ x,
    const int*   __restrict__ edge_index,
    const float* __restrict__ gf,
    const int*   __restrict__ labels,
    const float* __restrict__ se_w1, const float* __restrict__ se_b1,
    const float* __restrict__ se_w2, const float* __restrict__ se_b2,
    const float* __restrict__ pw1,  const float* __restrict__ pb1,
    const float* __restrict__ pw2,  const float* __restrict__ pb2,
    const float* __restrict__ vw1,  const float* __restrict__ vb1,
    const float* __restrict__ vw2,  const float* __restrict__ vb2,
    float* __restrict__ out,        // out[0]=loss (finalize), out[1..E]=actions
    float* __restrict__ ws_partial,
    int n_edges)
{
  extern __shared__ float smem[];
  float* sH    = smem;
  float* sA    = smem;              // A dbuf aliases sH during L1
  float* sW    = smem + SW_OFF;     // [2][8][256]
  float* sLoss = smem + SW_OFF;     // valid only after last chunk

  const int t  = threadIdx.x;
  const int e0 = blockIdx.x * TE;

  // register tile: 8 edges x 4 cols per thread over [64 x 256]
  const int tc  = t & 31;
  const int teh = t >> 5;
  const int te  = teh & 7;          // edge group: rows te*8 .. te*8+7
  const int ch  = teh >> 3;
  const int colBase = ch * 128 + tc * 4;

  // W-chunk staging slot: thread t stages float4 #t of an [8][256] chunk
  const int wr  = t >> 6;           // LDS dest is wave-uniform + lane*16
  const int wc4 = t & 63;

  // hoisted staging bases (strength reduction: chunk loops add immediates)
  const float* w1p = se_w1 + (size_t)wr * 256 + wc4 * 4;   // + c*2048
  const float* w2p = se_w2 + (size_t)wr * 256 + wc4 * 4;
  const float* w3p = (wc4 < 32) ? pw1 + (size_t)wr * 128 + wc4 * 4
                                : vw1 + (size_t)wr * 128 + (wc4 - 32) * 4;
  float* sWslot = sW + t * 4;                               // + b*2048

  v2f acc[8][2];   // [edge][col-pair]
  auto zero_acc = [&]() {
    #pragma unroll
    for (int i = 0; i < 8; ++i) {
      acc[i][0] = v2f{0.f, 0.f};
      acc[i][1] = v2f{0.f, 0.f};
    }
  };

  auto issueW1 = [&](int c, int b) { gld16(w1p + (size_t)c * 2048, sWslot + b * 2048); };
  auto issueW2 = [&](int c, int b) { gld16(w2p + (size_t)c * 2048, sWslot + b * 2048); };
  auto issueW3 = [&](int c, int b) { gld16(w3p + (size_t)c * 1024, sWslot + b * 2048); };

  // async A-tile gather into buffer b: [64][128] = 2048 float4, 4/thread.
  auto stageA_issue = [&](int seg, int b) {
    float* dst = sA + b * 8192;
    #pragma unroll
    for (int j = 0; j < 4; ++j) {
      int r  = (t >> 5) + j * 16;       // (t + j*512) >> 5
      int eg = e0 + r;
      bool v = eg < n_edges;
      int node;
      const float* src;
      if (seg == 0)      { node = v ? edge_index[eg] : 0;                   src = x;  }
      else if (seg == 1) { node = v ? edge_index[(size_t)n_edges + eg] : 0; src = x;  }
      else               { node = v ? edge_index[(size_t)n_edges + eg] : 0; src = gf; }
      gld16(&src[(size_t)node * 128 + tc * 4], &dst[(t + j * 512) * 4]);
    }
  };

  // acc += A[64 x 8](stride LDA) @ Wb[8][256]: 128 v_pk_fma_f32 per call.
  // Marshal-free: v4f LDS loads, pairs via shufflevector (even-aligned subregs);
  // 2-row interleave -> 4 independent acc chains (pk latency hidden in-wave).
  auto gemmC = [&](const float* Ak, const int LDA, const float* Wb) {
    const v4f* Wp = (const v4f*)(Wb + colBase);          // row stride 64 v4f
    const v4f* Ap = (const v4f*)(Ak + te * 8 * LDA);     // row stride LDA/4 v4f
    #pragma unroll
    for (int k4 = 0; k4 < 2; ++k4) {
      v2f w[4][2];
      #pragma unroll
      for (int dk = 0; dk < 4; ++dk) {
        v4f wv = Wp[(k4 * 4 + dk) * 64];
        w[dk][0] = __builtin_shufflevector(wv, wv, 0, 1);
        w[dk][1] = __builtin_shufflevector(wv, wv, 2, 3);
      }
      #pragma unroll
      for (int i = 0; i < 8; i += 2) {
        v4f a0 = Ap[(i * LDA + k4 * 4) >> 2];
        v4f a1 = Ap[((i + 1) * LDA + k4 * 4) >> 2];
        v2f a0lo = __builtin_shufflevector(a0, a0, 0, 1);
        v2f a0hi = __builtin_shufflevector(a0, a0, 2, 3);
        v2f a1lo = __builtin_shufflevector(a1, a1, 0, 1);
        v2f a1hi = __builtin_shufflevector(a1, a1, 2, 3);
        PK_LO(acc[i][0],     a0lo, w[0][0]);
        PK_LO(acc[i][1],     a0lo, w[0][1]);
        PK_LO(acc[i + 1][0], a1lo, w[0][0]);
        PK_LO(acc[i + 1][1], a1lo, w[0][1]);
        PK_HI(acc[i][0],     a0lo, w[1][0]);
        PK_HI(acc[i][1],     a0lo, w[1][1]);
        PK_HI(acc[i + 1][0], a1lo, w[1][0]);
        PK_HI(acc[i + 1][1], a1lo, w[1][1]);
        PK_LO(acc[i][0],     a0hi, w[2][0]);
        PK_LO(acc[i][1],     a0hi, w[2][1]);
        PK_LO(acc[i + 1][0], a1hi, w[2][0]);
        PK_LO(acc[i + 1][1], a1hi, w[2][1]);
        PK_HI(acc[i][0],     a0hi, w[3][0]);
        PK_HI(acc[i][1],     a0hi, w[3][1]);
        PK_HI(acc[i + 1][0], a1hi, w[3][0]);
        PK_HI(acc[i + 1][1], a1hi, w[3][1]);
      }
    }
  };

  // ---- prologue: W0 + A seg0 in flight ----
  issueW1(0, 0);
  stageA_issue(0, 0);
  __syncthreads();              // drains both (vmcnt(0) in syncthreads)

  zero_acc();

  // ===== Layer 1: 3 segments x 16 chunks; A double-buffered =====
  for (int seg = 0; seg < 3; ++seg) {
    const float* Ab = sA + (seg & 1) * 8192;
    if (seg < 2) stageA_issue(seg + 1, (seg + 1) & 1);   // prev buf freed at seg-1's last barrier
    #pragma unroll 4
    for (int kc = 0; kc < 16; ++kc) {
      int c = seg * 16 + kc;
      if (c < 47) issueW1(c + 1, (c + 1) & 1);
      else        issueW2(0, 0);               // cross-layer prefetch (48&1==0)
      gemmC(Ab + kc * 8, 128, sW + (c & 1) * 2048);
      __syncthreads();                         // W(c+1)+A drained; buf[c&1] free
    }
  }

  { // L1 epilogue: relu(acc+b1) -> sH (overwrites A dbuf; all A reads done)
    float4 b = *(const float4*)&se_b1[colBase];
    #pragma unroll
    for (int i = 0; i < 8; ++i) {
      float4 hv;
      hv.x = fmaxf(acc[i][0].x + b.x, 0.f);
      hv.y = fmaxf(acc[i][0].y + b.y, 0.f);
      hv.z = fmaxf(acc[i][1].x + b.z, 0.f);
      hv.w = fmaxf(acc[i][1].y + b.w, 0.f);
      *(float4*)&sH[(te * 8 + i) * 256 + colBase] = hv;
    }
    zero_acc();
  }
  __syncthreads();   // H1 visible; W2 chunk0 (issued at c=47) already drained

  // ================= Layer 2: 32 chunks (K=256) =================
  #pragma unroll 4
  for (int c = 0; c < 32; ++c) {
    if (c < 31) issueW2(c + 1, (c + 1) & 1);
    else        issueW3(0, 0);               // (global chunk 80)&1==0
    gemmC(sH + c * 8, 256, sW + (c & 1) * 2048);
    __syncthreads();
  }

  { // L2 epilogue: acc+b2 -> sH (no relu)
    float4 b = *(const float4*)&se_b2[colBase];
    #pragma unroll
    for (int i = 0; i < 8; ++i) {
      float4 hv;
      hv.x = acc[i][0].x + b.x;
      hv.y = acc[i][0].y + b.y;
      hv.z = acc[i][1].x + b.z;
      hv.w = acc[i][1].y + b.w;
      *(float4*)&sH[(te * 8 + i) * 256 + colBase] = hv;
    }
    zero_acc();
  }
  __syncthreads();

  // ============ Layer 3: 32 chunks (K=256), cols = [pw1|vw1] ============
  #pragma unroll 4
  for (int c = 0; c < 32; ++c) {
    if (c < 31) issueW3(c + 1, (c + 1) & 1);
    gemmC(sH + c * 8, 256, sW + (c & 1) * 2048);
    __syncthreads();
  }

  { // L3 epilogue: relu(acc + [pb1|vb1]) -> sH
    float4 b = (ch == 0) ? *(const float4*)&pb1[tc * 4] : *(const float4*)&vb1[tc * 4];
    #pragma unroll
    for (int i = 0; i < 8; ++i) {
      float4 hv;
      hv.x = fmaxf(acc[i][0].x + b.x, 0.f);
      hv.y = fmaxf(acc[i][0].y + b.y, 0.f);
      hv.z = fmaxf(acc[i][1].x + b.z, 0.f);
      hv.w = fmaxf(acc[i][1].y + b.w, 0.f);
      *(float4*)&sH[(te * 8 + i) * 256 + colBase] = hv;
    }
  }
  __syncthreads();   // also: W bufs now dead -> sLoss region valid

  // ================= Layer 4: heads (two 128-dots per edge) =================
  {
    int lk   = t & 3;          // k quarter
    int d    = t >> 2;         // 0..127
    int head = d >> 6;         // 0: policy, 1: value
    int edge = d & 63;         // 0..63
    const float* w2 = head ? vw2 : pw2;   // global, L2-hot
    float p = 0.f;
    #pragma unroll
    for (int kk = 0; kk < 32; kk += 4) {
      float4 r4 = *(const float4*)&sH[edge * 256 + head * 128 + lk * 32 + kk];
      float4 w4 = *(const float4*)&w2[lk * 32 + kk];
      p = fmaf(r4.x, w4.x, p);
      p = fmaf(r4.y, w4.y, p);
      p = fmaf(r4.z, w4.z, p);
      p = fmaf(r4.w, w4.w, p);
    }
    p += __shfl_xor(p, 1);
    p += __shfl_xor(p, 2);
    if (lk == 0) {
      int eg = e0 + edge;
      bool valid = eg < n_edges;
      if (head == 0) {
        float logit = p + pb2[0];
        if (valid) out[1 + eg] = (logit > 0.f) ? 1.f : 0.f;  // sigmoid(l)>0.5 <=> l>0
      } else {
        float term = 0.f;
        if (valid) {
          float z = p + vb2[0];
          int srcn = edge_index[eg];               // row index (L1-hot)
          float yv = (float)labels[srcn];
          term = fmaxf(z, 0.f) - z * yv + log1pf(expf(-fabsf(z)));
        }
        sLoss[edge] = term;
      }
    }
  }
  __syncthreads();
  if (t == 0) {
    float s = 0.f;
    #pragma unroll 4
    for (int i = 0; i < TE; ++i) s += sLoss[i];  // fixed order -> deterministic
    ws_partial[blockIdx.x] = s;
  }
}

__global__ void finalize_loss(const float* __restrict__ ws, float* __restrict__ out,
                              int n, double invE)
{
  __shared__ double sd[256];
  double a = 0.0;
  for (int i = threadIdx.x; i < n; i += 256) a += (double)ws[i];  // fixed order
  sd[threadIdx.x] = a;
  __syncthreads();
  for (int off = 128; off > 0; off >>= 1) {
    if ((int)threadIdx.x < off) sd[threadIdx.x] += sd[threadIdx.x + off];
    __syncthreads();
  }
  if (threadIdx.x == 0) out[0] = (float)(sd[0] * invE);
}

extern "C" void kernel_launch(void* const* d_in, const int* in_sizes, int n_in,
                              void* d_out, int out_size, void* d_ws, size_t ws_size,
                              hipStream_t stream) {
  const float* x      = (const float*)d_in[0];
  const int*   ei     = (const int*)  d_in[1];
  const float* gf     = (const float*)d_in[2];
  const int*   labels = (const int*)  d_in[3];
  const float* se_w1  = (const float*)d_in[4];
  const float* se_b1  = (const float*)d_in[5];
  const float* se_w2  = (const float*)d_in[6];
  const float* se_b2  = (const float*)d_in[7];
  const float* pw1    = (const float*)d_in[8];
  const float* pb1    = (const float*)d_in[9];
  const float* pw2    = (const float*)d_in[10];
  const float* pb2    = (const float*)d_in[11];
  const float* vw1    = (const float*)d_in[12];
  const float* vb1    = (const float*)d_in[13];
  const float* vw2    = (const float*)d_in[14];
  const float* vb2    = (const float*)d_in[15];

  int n_edges = in_sizes[1] / 2;
  int nblocks = (n_edges + TE - 1) / TE;
  float* out = (float*)d_out;
  float* ws  = (float*)d_ws;

  size_t shmem = SMEM_FLOATS * sizeof(float);  // 81920 B exactly -> 2 blocks/CU
  (void)hipFuncSetAttribute((const void*)fused_edge_mlp,
                            hipFuncAttributeMaxDynamicSharedMemorySize, (int)shmem);

  fused_edge_mlp<<<dim3(nblocks), dim3(NTHREADS), shmem, stream>>>(
      x, ei, gf, labels,
      se_w1, se_b1, se_w2, se_b2,
      pw1, pb1, pw2, pb2,
      vw1, vb1, vw2, vb2,
      out, ws, n_edges);

  finalize_loss<<<dim3(1), dim3(256), 0, stream>>>(ws, out, nblocks, 1.0 / (double)n_edges);
}